// Round 5
// baseline (395.508 us; speedup 1.0000x reference)
//
#include <hip/hip_runtime.h>
#include <hip/hip_fp16.h>

#define NN 3072
#define DD 256
#define NH 8
#define SPLIT 4
#define KT (NN / SPLIT / 64)   // 12 key-tiles of 64 per split
#define NKT2 (NN / 64)         // 48 global key tiles
#define LN2INV 1.4426950408889634f

typedef _Float16 h16;
typedef __attribute__((ext_vector_type(4))) _Float16 half4;
typedef __attribute__((ext_vector_type(8))) _Float16 half8;
typedef __attribute__((ext_vector_type(4))) float f32x4;

#if __has_builtin(__builtin_amdgcn_exp2f)
#define EXP2(x) __builtin_amdgcn_exp2f(x)
#else
#define EXP2(x) __expf((x) * 0.69314718056f)
#endif

// --------------------------------------------------------- async 16B stage ---
__device__ __forceinline__ void async16(const h16* g, h16* l, int lane) {
#if __has_builtin(__builtin_amdgcn_global_load_lds)
  __builtin_amdgcn_global_load_lds(
      (const __attribute__((address_space(1))) void*)(g + (size_t)lane * 8),
      (__attribute__((address_space(3))) void*)l, 16, 0, 0);
#else
  *(half8*)(l + lane * 8) = *(const half8*)(g + (size_t)lane * 8);
#endif
}

// ------------------------------------------------------------- aug writer ----
// qaug/kaug: 16-dim fp16 aug vectors (geo term via one MFMA, dims 12-15 zero).
// xzT3[kt2][chunk(8)][row(16)][8]: sum-MFMA A tiles {1,xh,yh,zh,xl,yl,zl,0..}.
__device__ inline void write_aug(int q, float x, float y, float z,
                                 h16* __restrict__ qaug, h16* __restrict__ kaug,
                                 h16* __restrict__ xzT3) {
  float sx = 0.5f * LN2INV * x, sy = 0.5f * LN2INV * y, sz = 0.5f * LN2INV * z;
  h16 shx = (h16)sx, shy = (h16)sy, shz = (h16)sz;
  h16 slx = (h16)(sx - (float)shx), sly = (h16)(sy - (float)shy), slz = (h16)(sz - (float)shz);
  h16 hx = (h16)x, hy = (h16)y, hz = (h16)z;
  h16 lx = (h16)(x - (float)hx), ly = (h16)(y - (float)hy), lz = (h16)(z - (float)hz);
  float n2n = -0.25f * LN2INV * (x * x + y * y + z * z);
  h16 nh = (h16)n2n, nl = (h16)(n2n - (float)nh);
  h16 qa[16], ka[16];
  #pragma unroll
  for (int i = 0; i < 16; ++i) { qa[i] = (h16)0.f; ka[i] = (h16)0.f; }
  qa[0] = shx; qa[1] = shy; qa[2] = shz;       // pairs A d0-2 = hk
  qa[3] = shx; qa[4] = shy; qa[5] = shz;       // pairs A d3-5 = lk
  qa[6] = slx; qa[7] = sly; qa[8] = slz;       // pairs A d6-8 = hk
  qa[9] = (h16)1.f; qa[10] = (h16)1.f;         // pairs key-norm hi/lo
  qa[11] = (h16)n2n;                           // query norm (row-const)
  ka[0] = hx; ka[1] = hy; ka[2] = hz;
  ka[3] = lx; ka[4] = ly; ka[5] = lz;
  ka[6] = hx; ka[7] = hy; ka[8] = hz;
  ka[9] = nh; ka[10] = nl;
  ka[11] = (h16)1.f;
  *(half8*)(qaug + (size_t)q * 16) = ((half8*)qa)[0];
  *(half8*)(qaug + (size_t)q * 16 + 8) = ((half8*)qa)[1];
  *(half8*)(kaug + (size_t)q * 16) = ((half8*)ka)[0];
  *(half8*)(kaug + (size_t)q * 16 + 8) = ((half8*)ka)[1];
  int kt2 = q >> 6, kk = q & 63;
  h16* b = xzT3 + ((size_t)kt2 << 10) + (kk >> 3) * 128 + (kk & 7);
  b[0] = (h16)1.f;
  b[8] = hx; b[16] = hy; b[24] = hz;
  b[32] = lx; b[40] = ly; b[48] = lz;
  #pragma unroll
  for (int r = 7; r < 16; ++r) b[r * 8] = (h16)0.f;
}

// ------------------------------------------------- convert + initial aug -----
__global__ __launch_bounds__(256) void k_convert(
    const float* __restrict__ x, const float* __restrict__ xyz,
    h16* __restrict__ xb, h16* __restrict__ qaug,
    h16* __restrict__ kaug, h16* __restrict__ xzT3) {
  int t = blockIdx.x * 256 + threadIdx.x;
  const int NX = NN * DD;
  if (t < NX) { xb[t] = (h16)x[t]; return; }
  int q = t - NX;
  if (q < NN) write_aug(q, xyz[q * 3], xyz[q * 3 + 1], xyz[q * 3 + 2], qaug, kaug, xzT3);
}

// --------------------------------------------------------- W transpose -------
// Coalesced fp32 reads + coalesced fp16 writes via 32x32 LDS tile.
__global__ __launch_bounds__(256) void k_wt(
    const float* __restrict__ Wq, const float* __restrict__ Wk,
    const float* __restrict__ Wv, const float* __restrict__ Wo,
    h16* __restrict__ wtq, h16* __restrict__ wtk, h16* __restrict__ wtv,
    h16* __restrict__ wto) {
  __shared__ float tile[32][33];
  int m = blockIdx.z;
  const float* W = (m == 0) ? Wq : (m == 1) ? Wk : (m == 2) ? Wv : Wo;
  h16* wt = (m == 0) ? wtq : (m == 1) ? wtk : (m == 2) ? wtv : wto;
  int n0 = blockIdx.x * 32, k0 = blockIdx.y * 32;
  int tx = threadIdx.x & 31, ty = threadIdx.x >> 5;   // 32 x 8
  #pragma unroll
  for (int i = 0; i < 4; ++i)
    tile[ty + i * 8][tx] = W[(size_t)(k0 + ty + i * 8) * 256 + n0 + tx];
  __syncthreads();
  #pragma unroll
  for (int i = 0; i < 4; ++i)
    wt[(size_t)(n0 + ty + i * 8) * 256 + k0 + tx] = (h16)tile[tx][ty + i * 8];
}

// ---------------------------------------------------------------- prep dy ----
// dynT3[qt][kt2][chunk(2)][lane(64)][8]: staged-linear MFMA C-fragment tiles.
// Coalesced: 16x256 tile into LDS, then half8 fragments stored 16B coalesced.
__global__ __launch_bounds__(256) void k_prep(
    const float* __restrict__ dy, const int* __restrict__ dm,
    const int* __restrict__ bim, h16* __restrict__ dynT3) {
  __shared__ h16 sv[16][264];
  int qt = blockIdx.y;                 // 0..191  (16 query rows)
  int cb = blockIdx.x;                 // 0..11   (256 key cols)
  int t = threadIdx.x;
  int col = cb * 256 + t;
  #pragma unroll
  for (int r = 0; r < 16; ++r) {
    int row = qt * 16 + r;
    size_t idx = (size_t)row * NN + col;
    bool diag = (row == col);
    bool valid = (dm[idx] != 0 && bim[idx] != 0) || diag;
    float v = valid ? (-LN2INV * (dy[idx] + (diag ? 2.5e-5f : 0.f))) : -43281.f;
    sv[r][t] = (h16)v;
  }
  __syncthreads();
  #pragma unroll
  for (int s2 = 0; s2 < 2; ++s2) {
    int s = t + s2 * 256;              // 0..511 : 4 tiles x 128 half8 slots
    int tile = s >> 7;
    int sl = s & 127;                  // chunk*64 + lane
    int chunk = sl >> 6;
    int lane = sl & 63;
    int row = lane & 15, quad = lane >> 4;
    int base = tile * 64 + chunk * 32 + quad * 4;
    half4 lo = *(const half4*)&sv[row][base];
    half4 hi = *(const half4*)&sv[row][base + 16];
    half8 o;
    #pragma unroll
    for (int j = 0; j < 4; ++j) { o[j] = lo[j]; o[j + 4] = hi[j]; }
    h16* dst = dynT3 + (((size_t)qt * NKT2 + (cb * 4 + tile)) << 10) + sl * 8;
    *(half8*)dst = o;
  }
}

// ------------------------------------------------------------------- gemm ----
// mode 0: fp16 row-major *scale; mode 1: fp16 [d][token]; mode 2: fp32 +resid;
// mode 3: fp16 per-head contiguous kbh[h][token][32]
__device__ inline void gemm_body(const h16* __restrict__ A, const h16* __restrict__ Bt,
                                 const float* __restrict__ bias, void* __restrict__ out,
                                 const float* __restrict__ resid, int M, int mode,
                                 float scale, int bx, int by) {
  int lane = threadIdx.x & 63;
  int wave = threadIdx.x >> 6;
  int col = lane & 15, quad = lane >> 4;
  int m0 = bx * 32;
  int n0 = by * 64 + wave * 16;
  f32x4 acc[2];
  acc[0] = (f32x4){0.f, 0.f, 0.f, 0.f};
  acc[1] = (f32x4){0.f, 0.f, 0.f, 0.f};
  #pragma unroll
  for (int kk = 0; kk < DD; kk += 32) {
    half8 b = *(const half8*)(Bt + (size_t)(n0 + col) * DD + kk + quad * 8);
    #pragma unroll
    for (int mr = 0; mr < 2; ++mr) {
      half8 a = *(const half8*)(A + (size_t)(m0 + mr * 16 + col) * DD + kk + quad * 8);
      acc[mr] = __builtin_amdgcn_mfma_f32_16x16x32_f16(a, b, acc[mr], 0, 0, 0);
    }
  }
  float bb = bias[n0 + col];
  #pragma unroll
  for (int mr = 0; mr < 2; ++mr) {
    #pragma unroll
    for (int r = 0; r < 4; ++r) {
      int m = m0 + mr * 16 + quad * 4 + r;
      int n = n0 + col;
      float v = acc[mr][r] + bb;
      if (mode == 0)      ((h16*)out)[(size_t)m * DD + n] = (h16)(v * scale);
      else if (mode == 1) ((h16*)out)[(size_t)n * M + m] = (h16)v;
      else if (mode == 3) ((h16*)out)[((size_t)(n >> 5) * NN + m) * 32 + (n & 31)] = (h16)v;
      else ((float*)out)[(size_t)m * DD + n] = v + resid[(size_t)m * DD + n];
    }
  }
}

__global__ __launch_bounds__(256) void k_gemm(
    const h16* __restrict__ A, const h16* __restrict__ Bt,
    const float* __restrict__ bias, void* __restrict__ out,
    const float* __restrict__ resid, int M, int mode, float scale) {
  gemm_body(A, Bt, bias, out, resid, M, mode, scale, blockIdx.x, blockIdx.y);
}

__global__ __launch_bounds__(256) void k_gemm3(
    const h16* __restrict__ A, const h16* __restrict__ wtq,
    const h16* __restrict__ wtk, const h16* __restrict__ wtv,
    const float* __restrict__ bq, const float* __restrict__ bk,
    const float* __restrict__ bv, h16* __restrict__ qb, h16* __restrict__ kbh,
    h16* __restrict__ vt, float qscale) {
  int z = blockIdx.z;
  const h16* Bt = (z == 0) ? wtq : (z == 1) ? wtk : wtv;
  const float* bias = (z == 0) ? bq : (z == 1) ? bk : bv;
  void* out = (z == 0) ? (void*)qb : (z == 1) ? (void*)kbh : (void*)vt;
  int mode = (z == 0) ? 0 : (z == 1) ? 3 : 1;
  gemm_body(A, Bt, bias, out, nullptr, NN, mode, (z == 0) ? qscale : 1.f,
            blockIdx.x, blockIdx.y);
}

// ------------------------------------------------------------- mean shift ----
// 4-wave blocks (4 heads each; 2 blocks cover the 8 heads of one (qt,split)).
// Theory: 512-thread barrier-synced blocks left the CU with ~1.5 independent
// schedulable units -> stalls exposed. 4-wave blocks give ~7 independent
// barrier domains per CU so one block's stage/barrier hides under others'
// compute. Adjacent blockIdx.x pairs share (qt,kt) tiles -> dynT3 re-read
// dedups in L2.
__device__ __forceinline__ void stage_tile(int w, int lane, int qt, int kt2,
                                           const h16* __restrict__ dynT3,
                                           const h16* __restrict__ kaug,
                                           const h16* __restrict__ xzT3,
                                           h16* bdy, h16* bka, h16* bxz) {
  if (w == 0) {
    const h16* g = dynT3 + (((size_t)qt * NKT2 + kt2) << 10);
    async16(g, bdy, lane);
    async16(g + 512, bdy + 512, lane);
  } else if (w == 1) {
    const h16* g = kaug + ((size_t)kt2 << 10);
    async16(g, bka, lane);
    async16(g + 512, bka + 512, lane);
  } else if (w == 2) {
    const h16* g = xzT3 + ((size_t)kt2 << 10);
    async16(g, bxz, lane);
    async16(g + 512, bxz + 512, lane);
  }
}

__device__ __forceinline__ void ldkf(const h16* __restrict__ kbh_h, int k0,
                                     int col, int quad, half8 kf[4]) {
  #pragma unroll
  for (int f = 0; f < 4; ++f)
    kf[f] = *(const half8*)(kbh_h + (size_t)(k0 + f * 16 + col) * 32 + quad * 8);
}

template <int LAST>
__device__ __forceinline__ void ms_compute(
    const h16* __restrict__ bdy, const h16* __restrict__ bka,
    const h16* __restrict__ bxz, const half8 kf[4], half8 qaf, half8 qf,
    const h16* __restrict__ vA, const h16* __restrict__ vB,
    h16 (*s_ph)[72], int lane, int col, int quad,
    f32x4& accS, f32x4& fc0, f32x4& fc1) {
  half8 kz = {};
  half8 dv0 = *(const half8*)(bdy + lane * 8);
  half8 dv1 = *(const half8*)(bdy + 512 + lane * 8);
  #pragma unroll
  for (int f = 0; f < 4; ++f) {
    half8 ka = (quad < 2) ? *(const half8*)(bka + (f * 16 + col) * 16 + quad * 8) : kz;
    half8 dv = (f & 2) ? dv1 : dv0;
    f32x4 cc;
    #pragma unroll
    for (int r = 0; r < 4; ++r) cc[r] = (float)dv[(f & 1) * 4 + r];
    f32x4 g = __builtin_amdgcn_mfma_f32_16x16x32_f16(ka, qaf, cc, 0, 0, 0);
    f32x4 s = __builtin_amdgcn_mfma_f32_16x16x32_f16(kf[f], qf, g, 0, 0, 0);
    half4 pv;
    #pragma unroll
    for (int r = 0; r < 4; ++r) pv[r] = (h16)EXP2(s[r]);
    *(half4*)&s_ph[col][f * 16 + quad * 4] = pv;
  }
  #pragma unroll
  for (int c = 0; c < 2; ++c) {
    half8 pf = *(const half8*)&s_ph[col][c * 32 + quad * 8];
    half8 xf = *(const half8*)(bxz + ((c * 4 + quad) * 16 + col) * 8);
    accS = __builtin_amdgcn_mfma_f32_16x16x32_f16(xf, pf, accS, 0, 0, 0);
    if (LAST) {
      half8 v0 = *(const half8*)(vA + c * 32 + quad * 8);
      half8 v1 = *(const half8*)(vB + c * 32 + quad * 8);
      fc0 = __builtin_amdgcn_mfma_f32_16x16x32_f16(v0, pf, fc0, 0, 0, 0);
      fc1 = __builtin_amdgcn_mfma_f32_16x16x32_f16(v1, pf, fc1, 0, 0, 0);
    }
  }
}

template <int LAST>
__global__ __launch_bounds__(256, 4) void k_msattn(
    const h16* __restrict__ qb, const h16* __restrict__ kbh,
    const h16* __restrict__ vt, const h16* __restrict__ dynT3,
    const h16* __restrict__ qaug, const h16* __restrict__ kaug,
    const h16* __restrict__ xzT3, float* __restrict__ den_s,
    float* __restrict__ axh_s, float* __restrict__ axl_s,
    float* __restrict__ numT) {
  __shared__ h16 s_dy[2][1024];
  __shared__ h16 s_ka[2][1024];
  __shared__ h16 s_xz[2][1024];
  __shared__ h16 s_p[4][16][72];
  const int tid = threadIdx.x;
  const int w = tid >> 6;               // wave 0..3
  const int lane = tid & 63;
  const int col = lane & 15;
  const int quad = lane >> 4;
  const int qt = blockIdx.x >> 1;
  const int hg = blockIdx.x & 1;        // head group 0/1
  const int h = hg * 4 + w;             // global head
  const int q0 = qt * 16;
  const int tb = blockIdx.y * KT;

  half8 kz = {};
  half8 qf = *(const half8*)(qb + (size_t)(q0 + col) * DD + h * 32 + quad * 8);
  half8 qaf = (quad < 2) ? *(const half8*)(qaug + (size_t)(q0 + col) * 16 + quad * 8) : kz;
  const h16* kbh_h = kbh + (size_t)h * NN * 32;
  const h16* vtA = vt + (size_t)(h * 32 + col) * NN;
  const h16* vtB = vt + (size_t)(h * 32 + 16 + col) * NN;
  f32x4 accS = (f32x4){0.f, 0.f, 0.f, 0.f};
  f32x4 fc0 = (f32x4){0.f, 0.f, 0.f, 0.f};
  f32x4 fc1 = (f32x4){0.f, 0.f, 0.f, 0.f};
  half8 kfA[4], kfB[4];

  stage_tile(w, lane, qt, tb, dynT3, kaug, xzT3, s_dy[0], s_ka[0], s_xz[0]);
  ldkf(kbh_h, tb * 64, col, quad, kfA);
  __syncthreads();          // drains async stage + kfA
  #pragma unroll 1
  for (int kt = 0; kt < KT; kt += 2) {
    int t1 = tb + kt + 1;
    stage_tile(w, lane, qt, t1, dynT3, kaug, xzT3, s_dy[1], s_ka[1], s_xz[1]);
    ldkf(kbh_h, t1 * 64, col, quad, kfB);
    ms_compute<LAST>(s_dy[0], s_ka[0], s_xz[0], kfA, qaf, qf,
                     vtA + (tb + kt) * 64, vtB + (tb + kt) * 64,
                     s_p[w], lane, col, quad, accS, fc0, fc1);
    __syncthreads();        // buf1 + kfB now resident
    int t2 = (kt + 2 < KT) ? tb + kt + 2 : t1;
    if (kt + 2 < KT)
      stage_tile(w, lane, qt, t2, dynT3, kaug, xzT3, s_dy[0], s_ka[0], s_xz[0]);
    ldkf(kbh_h, t2 * 64, col, quad, kfA);
    ms_compute<LAST>(s_dy[1], s_ka[1], s_xz[1], kfB, qaf, qf,
                     vtA + t1 * 64, vtB + t1 * 64,
                     s_p[w], lane, col, quad, accS, fc0, fc1);
    __syncthreads();
  }

  // accS D rows: 0=den, 1-3=num_hi, 4-6=num_lo
  int q = q0 + col;
  size_t sidx = (size_t)(blockIdx.y * NH + h) * NN + q;
  if (quad == 0) {
    den_s[sidx] = accS[0];
    axh_s[sidx * 3 + 0] = accS[1];
    axh_s[sidx * 3 + 1] = accS[2];
    axh_s[sidx * 3 + 2] = accS[3];
  } else if (quad == 1) {
    axl_s[sidx * 3 + 0] = accS[0];
    axl_s[sidx * 3 + 1] = accS[1];
    axl_s[sidx * 3 + 2] = accS[2];
  }
  if (LAST) {
    #pragma unroll
    for (int r = 0; r < 4; ++r) {
      atomicAdd(&numT[(size_t)(h * 32 + quad * 4 + r) * NN + q], fc0[r]);
      atomicAdd(&numT[(size_t)(h * 32 + 16 + quad * 4 + r) * NN + q], fc1[r]);
    }
  }
}

// ---------------------------------------------------------------- combine ----
__global__ __launch_bounds__(256) void k_combine(
    const float* __restrict__ den_s, const float* __restrict__ axh_s,
    const float* __restrict__ axl_s, float* __restrict__ den_tot,
    h16* __restrict__ qaug, h16* __restrict__ kaug, h16* __restrict__ xzT3,
    float* __restrict__ out3) {
  int q = blockIdx.x * 256 + threadIdx.x;
  if (q >= NN) return;
  float X = 0.f, Y = 0.f, Z = 0.f;
  #pragma unroll
  for (int h = 0; h < NH; ++h) {
    float d = 0.f, x = 0.f, y = 0.f, z = 0.f;
    #pragma unroll
    for (int s = 0; s < SPLIT; ++s) {
      size_t idx = (size_t)(s * NH + h) * NN + q;
      d += den_s[idx];
      x += axh_s[idx * 3 + 0] + axl_s[idx * 3 + 0];
      y += axh_s[idx * 3 + 1] + axl_s[idx * 3 + 1];
      z += axh_s[idx * 3 + 2] + axl_s[idx * 3 + 2];
    }
    den_tot[h * NN + q] = d;
    float inv = 0.125f / d;
    X = fmaf(x, inv, X);
    Y = fmaf(y, inv, Y);
    Z = fmaf(z, inv, Z);
  }
  if (out3) {
    out3[q * 3 + 0] = X;
    out3[q * 3 + 1] = Y;
    out3[q * 3 + 2] = Z;
  } else {
    write_aug(q, X, Y, Z, qaug, kaug, xzT3);
  }
}

// ----------------------------------------------------------------- finish ----
__global__ __launch_bounds__(256) void k_finish(
    const float* __restrict__ numT, const float* __restrict__ den_tot,
    h16* __restrict__ featb) {
  __shared__ float tile[32][33];
  int q0 = blockIdx.x * 32, d0 = blockIdx.y * 32;
  int tx = threadIdx.x & 31, ty = threadIdx.x >> 5;   // 32 x 8
  #pragma unroll
  for (int i = 0; i < 4; ++i)
    tile[ty + i * 8][tx] = numT[(size_t)(d0 + ty + i * 8) * NN + q0 + tx];
  __syncthreads();
  int h = d0 >> 5;
  #pragma unroll
  for (int i = 0; i < 4; ++i) {
    int q = q0 + ty + i * 8;
    float inv = 1.f / den_tot[h * NN + q];
    featb[(size_t)q * DD + d0 + tx] = (h16)(tile[tx][ty + i * 8] * inv);
  }
}

// ----------------------------------------------------------------- launch ----
extern "C" void kernel_launch(void* const* d_in, const int* in_sizes, int n_in,
                              void* d_out, int out_size, void* d_ws, size_t ws_size,
                              hipStream_t stream) {
  const float* x   = (const float*)d_in[0];
  const float* xyz = (const float*)d_in[1];
  const float* dy  = (const float*)d_in[2];
  const int* dm    = (const int*)d_in[3];
  const int* bim   = (const int*)d_in[4];
  const float* Wq = (const float*)d_in[5];
  const float* bq = (const float*)d_in[6];
  const float* Wk = (const float*)d_in[7];
  const float* bk = (const float*)d_in[8];
  const float* Wv = (const float*)d_in[9];
  const float* bv = (const float*)d_in[10];
  const float* Wo = (const float*)d_in[11];
  const float* bo = (const float*)d_in[12];

  char* p = (char*)d_ws;
  h16* xb  = (h16*)p; p += (size_t)NN * DD * 2;
  h16* wtq = (h16*)p; p += 256 * 256 * 2;
  h16* wtk = (h16*)p; p += 256 * 256 * 2;
  h16* wtv = (h16*)p; p += 256 * 256 * 2;
  h16* wto = (h16*)p; p += 256 * 256 * 2;
  h16* qb    = (h16*)p; p += (size_t)NN * DD * 2;
  h16* kbh   = (h16*)p; p += (size_t)NN * DD * 2;
  h16* vt    = (h16*)p; p += (size_t)NN * DD * 2;
  h16* featb = (h16*)p; p += (size_t)NN * DD * 2;
  h16* dynT3 = (h16*)p; p += (size_t)NN * NN * 2;
  h16* qaug  = (h16*)p; p += (size_t)NN * 16 * 2;
  h16* kaug  = (h16*)p; p += (size_t)NN * 16 * 2;
  h16* xzT3  = (h16*)p; p += (size_t)NKT2 * 1024 * 2;
  float* den_s = (float*)p; p += (size_t)SPLIT * NH * NN * 4;
  float* axh_s = (float*)p; p += (size_t)SPLIT * NH * NN * 3 * 4;
  float* axl_s = (float*)p; p += (size_t)SPLIT * NH * NN * 3 * 4;
  float* den_tot = (float*)p; p += (size_t)NH * NN * 4;
  float* numT = (float*)p; p += (size_t)DD * NN * 4;

  hipMemsetAsync(numT, 0, (size_t)DD * NN * 4, stream);
  k_convert<<<(NN * DD + NN + 255) / 256, 256, 0, stream>>>(x, xyz, xb, qaug,
                                                            kaug, xzT3);
  k_wt<<<dim3(8, 8, 4), 256, 0, stream>>>(Wq, Wk, Wv, Wo, wtq, wtk, wtv, wto);
  k_prep<<<dim3(12, 192), 256, 0, stream>>>(dy, dm, bim, dynT3);
  k_gemm3<<<dim3(96, 4, 3), 256, 0, stream>>>(xb, wtq, wtk, wtv, bq, bk, bv,
                                              qb, kbh, vt,
                                              0.17677669529663689f * LN2INV);

  float* xyz_final = (float*)d_out;            // output 0: [3072,3]
  float* out_final = (float*)d_out + NN * 3;   // output 1: [3072,256]

  k_msattn<0><<<dim3(NN / 16 * 2, SPLIT), 256, 0, stream>>>(
      qb, kbh, vt, dynT3, qaug, kaug, xzT3, den_s, axh_s, axl_s, nullptr);
  k_combine<<<12, 256, 0, stream>>>(den_s, axh_s, axl_s, den_tot,
                                    qaug, kaug, xzT3, nullptr);
  k_msattn<0><<<dim3(NN / 16 * 2, SPLIT), 256, 0, stream>>>(
      qb, kbh, vt, dynT3, qaug, kaug, xzT3, den_s, axh_s, axl_s, nullptr);
  k_combine<<<12, 256, 0, stream>>>(den_s, axh_s, axl_s, den_tot,
                                    qaug, kaug, xzT3, nullptr);
  k_msattn<1><<<dim3(NN / 16 * 2, SPLIT), 256, 0, stream>>>(
      qb, kbh, vt, dynT3, qaug, kaug, xzT3, den_s, axh_s, axl_s, numT);
  k_combine<<<12, 256, 0, stream>>>(den_s, axh_s, axl_s, den_tot,
                                    nullptr, nullptr, nullptr, xyz_final);
  k_finish<<<dim3(96, 8), 256, 0, stream>>>(numT, den_tot, featb);
  k_gemm<<<dim3(96, 4), 256, 0, stream>>>(featb, wto, bo, out_final, x, NN, 2, 1.f);
}

// Round 7
// 373.274 us; speedup vs baseline: 1.0596x; 1.0596x over previous
//
#include <hip/hip_runtime.h>
#include <hip/hip_fp16.h>

#define NN 3072
#define DD 256
#define NH 8
#define SPLIT 4
#define KT (NN / SPLIT / 64)   // 12 key-tiles of 64 per split
#define NKT2 (NN / 64)         // 48 global key tiles
#define VHALF ((NN / 16) * 256)   // 49152: stride between v-dim halves
#define LN2INV 1.4426950408889634f

typedef _Float16 h16;
typedef __attribute__((ext_vector_type(4))) _Float16 half4;
typedef __attribute__((ext_vector_type(8))) _Float16 half8;
typedef __attribute__((ext_vector_type(4))) float f32x4;

#if __has_builtin(__builtin_amdgcn_exp2f)
#define EXP2(x) __builtin_amdgcn_exp2f(x)
#else
#define EXP2(x) __expf((x) * 0.69314718056f)
#endif

// K=16 f16 MFMA (legacy naming: no underscore before f16 -- gfx950 keeps it).
// B-fragment layout (k=quad*4+j, n=lane&15) EXACTLY matches the C-fragment of
// the score MFMA -> P feeds PV/sum MFMAs straight from registers.
#define MFMA16(a, b, c) __builtin_amdgcn_mfma_f32_16x16x16f16(a, b, c, 0, 0, 0)

// --------------------------------------------------------- async 16B stage ---
__device__ __forceinline__ void async16(const h16* g, h16* l, int lane) {
#if __has_builtin(__builtin_amdgcn_global_load_lds)
  __builtin_amdgcn_global_load_lds(
      (const __attribute__((address_space(1))) void*)(g + (size_t)lane * 8),
      (__attribute__((address_space(3))) void*)l, 16, 0, 0);
#else
  *(half8*)(l + lane * 8) = *(const half8*)(g + (size_t)lane * 8);
#endif
}

// ------------------------------------------------------------- aug writer ----
// qaug/kaug: 16-dim fp16 aug vectors (geo term via one MFMA, dims 12-15 zero).
// xzT3 layout: A-operand tiles for 16x16x16 MFMA.
// xzT3[kt2][f(4)][quad(4)][m(16)][j(4)]: comp[m] of key kt2*64+f*16+quad*4+j,
// comp = {1, xh, yh, zh, xl, yl, zl, 0...}.
__device__ inline void write_aug(int q, float x, float y, float z,
                                 h16* __restrict__ qaug, h16* __restrict__ kaug,
                                 h16* __restrict__ xzT3) {
  float sx = 0.5f * LN2INV * x, sy = 0.5f * LN2INV * y, sz = 0.5f * LN2INV * z;
  h16 shx = (h16)sx, shy = (h16)sy, shz = (h16)sz;
  h16 slx = (h16)(sx - (float)shx), sly = (h16)(sy - (float)shy), slz = (h16)(sz - (float)shz);
  h16 hx = (h16)x, hy = (h16)y, hz = (h16)z;
  h16 lx = (h16)(x - (float)hx), ly = (h16)(y - (float)hy), lz = (h16)(z - (float)hz);
  float n2n = -0.25f * LN2INV * (x * x + y * y + z * z);
  h16 nh = (h16)n2n, nl = (h16)(n2n - (float)nh);
  h16 qa[16], ka[16];
  #pragma unroll
  for (int i = 0; i < 16; ++i) { qa[i] = (h16)0.f; ka[i] = (h16)0.f; }
  qa[0] = shx; qa[1] = shy; qa[2] = shz;       // pairs A d0-2 = hk
  qa[3] = shx; qa[4] = shy; qa[5] = shz;       // pairs A d3-5 = lk
  qa[6] = slx; qa[7] = sly; qa[8] = slz;       // pairs A d6-8 = hk
  qa[9] = (h16)1.f; qa[10] = (h16)1.f;         // pairs key-norm hi/lo
  qa[11] = (h16)n2n;                           // query norm (row-const)
  ka[0] = hx; ka[1] = hy; ka[2] = hz;
  ka[3] = lx; ka[4] = ly; ka[5] = lz;
  ka[6] = hx; ka[7] = hy; ka[8] = hz;
  ka[9] = nh; ka[10] = nl;
  ka[11] = (h16)1.f;
  *(half8*)(qaug + (size_t)q * 16) = ((half8*)qa)[0];
  *(half8*)(qaug + (size_t)q * 16 + 8) = ((half8*)qa)[1];
  *(half8*)(kaug + (size_t)q * 16) = ((half8*)ka)[0];
  *(half8*)(kaug + (size_t)q * 16 + 8) = ((half8*)ka)[1];
  int kt2 = q >> 6, kk = q & 63;
  int f = kk >> 4, qd = (kk >> 2) & 3, j = kk & 3;
  h16* b = xzT3 + ((size_t)kt2 << 10) + f * 256 + qd * 64 + j;
  b[0] = (h16)1.f;
  b[4] = hx; b[8] = hy; b[12] = hz;
  b[16] = lx; b[20] = ly; b[24] = lz;
  #pragma unroll
  for (int m = 7; m < 16; ++m) b[m * 4] = (h16)0.f;
}

// ------------------------------------------------- convert + initial aug -----
__global__ __launch_bounds__(256) void k_convert(
    const float* __restrict__ x, const float* __restrict__ xyz,
    h16* __restrict__ xb, h16* __restrict__ qaug,
    h16* __restrict__ kaug, h16* __restrict__ xzT3) {
  int t = blockIdx.x * 256 + threadIdx.x;
  const int NX = NN * DD;
  if (t < NX) { xb[t] = (h16)x[t]; return; }
  int q = t - NX;
  if (q < NN) write_aug(q, xyz[q * 3], xyz[q * 3 + 1], xyz[q * 3 + 2], qaug, kaug, xzT3);
}

// --------------------------------------------------------- W transpose -------
__global__ __launch_bounds__(256) void k_wt(
    const float* __restrict__ Wq, const float* __restrict__ Wk,
    const float* __restrict__ Wv, const float* __restrict__ Wo,
    h16* __restrict__ wtq, h16* __restrict__ wtk, h16* __restrict__ wtv,
    h16* __restrict__ wto) {
  __shared__ float tile[32][33];
  int m = blockIdx.z;
  const float* W = (m == 0) ? Wq : (m == 1) ? Wk : (m == 2) ? Wv : Wo;
  h16* wt = (m == 0) ? wtq : (m == 1) ? wtk : (m == 2) ? wtv : wto;
  int n0 = blockIdx.x * 32, k0 = blockIdx.y * 32;
  int tx = threadIdx.x & 31, ty = threadIdx.x >> 5;   // 32 x 8
  #pragma unroll
  for (int i = 0; i < 4; ++i)
    tile[ty + i * 8][tx] = W[(size_t)(k0 + ty + i * 8) * 256 + n0 + tx];
  __syncthreads();
  #pragma unroll
  for (int i = 0; i < 4; ++i)
    wt[(size_t)(n0 + ty + i * 8) * 256 + k0 + tx] = (h16)tile[tx][ty + i * 8];
}

// ---------------------------------------------------------------- prep dy ----
// vec4 loads (48 independent loads/thread -> deep MLP), bitwise mask (no
// short-circuit dependent loads), 1024-col blocks, coalesced half8 stores.
__global__ __launch_bounds__(256) void k_prep(
    const float* __restrict__ dy, const int* __restrict__ dm,
    const int* __restrict__ bim, h16* __restrict__ dynT3) {
  __shared__ h16 sv[16][1036];
  int qt = blockIdx.y;                 // 0..191  (16 query rows)
  int cb = blockIdx.x;                 // 0..2    (1024 key cols)
  int t = threadIdx.x;
  int c0 = cb * 1024 + t * 4;
  #pragma unroll
  for (int r = 0; r < 16; ++r) {
    int row = qt * 16 + r;
    size_t idx = (size_t)row * NN + c0;
    int4 m4 = *(const int4*)(dm + idx);
    int4 b4 = *(const int4*)(bim + idx);
    float4 d4 = *(const float4*)(dy + idx);
    h16* s = &sv[r][t * 4];
    int mm[4] = {m4.x & b4.x, m4.y & b4.y, m4.z & b4.z, m4.w & b4.w};
    float dd[4] = {d4.x, d4.y, d4.z, d4.w};
    #pragma unroll
    for (int j = 0; j < 4; ++j) {
      bool diag = (row == c0 + j);
      bool valid = (mm[j] != 0) | diag;
      s[j] = (h16)(valid ? (-LN2INV * (dd[j] + (diag ? 2.5e-5f : 0.f))) : -43281.f);
    }
  }
  __syncthreads();
  #pragma unroll
  for (int s2 = 0; s2 < 8; ++s2) {
    int s = t + s2 * 256;              // 0..2047 : 16 tiles x 128 half8 slots
    int tile = s >> 7;
    int sl = s & 127;                  // chunk*64 + lane
    int chunk = sl >> 6;
    int lane = sl & 63;
    int row = lane & 15, quad = lane >> 4;
    int base = tile * 64 + chunk * 32 + quad * 4;
    half4 lo = *(const half4*)&sv[row][base];
    half4 hi = *(const half4*)&sv[row][base + 16];
    half8 o;
    #pragma unroll
    for (int j = 0; j < 4; ++j) { o[j] = lo[j]; o[j + 4] = hi[j]; }
    h16* dst = dynT3 + (((size_t)qt * NKT2 + (cb * 16 + tile)) << 10) + sl * 8;
    *(half8*)dst = o;
  }
}

// ------------------------------------------------------------------- gemm ----
// mode 0: fp16 row-major *scale; mode 2: fp32 +resid;
// mode 3: fp16 per-head contiguous kbh[h][token][32];
// mode 4: fp16 MFMA-A-layout vA[h*2+half][tile(192)][quad(4)][dim(16)][j(4)]
__device__ inline void gemm_body(const h16* __restrict__ A, const h16* __restrict__ Bt,
                                 const float* __restrict__ bias, void* __restrict__ out,
                                 const float* __restrict__ resid, int M, int mode,
                                 float scale, int bx, int by) {
  int lane = threadIdx.x & 63;
  int wave = threadIdx.x >> 6;
  int col = lane & 15, quad = lane >> 4;
  int m0 = bx * 32;
  int n0 = by * 64 + wave * 16;
  f32x4 acc[2];
  acc[0] = (f32x4){0.f, 0.f, 0.f, 0.f};
  acc[1] = (f32x4){0.f, 0.f, 0.f, 0.f};
  #pragma unroll
  for (int kk = 0; kk < DD; kk += 32) {
    half8 b = *(const half8*)(Bt + (size_t)(n0 + col) * DD + kk + quad * 8);
    #pragma unroll
    for (int mr = 0; mr < 2; ++mr) {
      half8 a = *(const half8*)(A + (size_t)(m0 + mr * 16 + col) * DD + kk + quad * 8);
      acc[mr] = __builtin_amdgcn_mfma_f32_16x16x32_f16(a, b, acc[mr], 0, 0, 0);
    }
  }
  float bb = bias[n0 + col];
  #pragma unroll
  for (int mr = 0; mr < 2; ++mr) {
    #pragma unroll
    for (int r = 0; r < 4; ++r) {
      int m = m0 + mr * 16 + quad * 4 + r;
      int n = n0 + col;
      float v = acc[mr][r] + bb;
      if (mode == 0)      ((h16*)out)[(size_t)m * DD + n] = (h16)(v * scale);
      else if (mode == 3) ((h16*)out)[((size_t)(n >> 5) * NN + m) * 32 + (n & 31)] = (h16)v;
      else if (mode == 4) {
        int hh = n >> 5, d = n & 31;
        size_t a = ((((size_t)hh * 2 + (d >> 4)) * (NN / 16) + (m >> 4)) * 64 +
                    ((m >> 2) & 3) * 16 + (d & 15)) * 4 + (m & 3);
        ((h16*)out)[a] = (h16)v;
      }
      else ((float*)out)[(size_t)m * DD + n] = v + resid[(size_t)m * DD + n];
    }
  }
}

__global__ __launch_bounds__(256) void k_gemm(
    const h16* __restrict__ A, const h16* __restrict__ Bt,
    const float* __restrict__ bias, void* __restrict__ out,
    const float* __restrict__ resid, int M, int mode, float scale) {
  gemm_body(A, Bt, bias, out, resid, M, mode, scale, blockIdx.x, blockIdx.y);
}

__global__ __launch_bounds__(256) void k_gemm3(
    const h16* __restrict__ A, const h16* __restrict__ wtq,
    const h16* __restrict__ wtk, const h16* __restrict__ wtv,
    const float* __restrict__ bq, const float* __restrict__ bk,
    const float* __restrict__ bv, h16* __restrict__ qb, h16* __restrict__ kbh,
    h16* __restrict__ vA, float qscale) {
  int z = blockIdx.z;
  const h16* Bt = (z == 0) ? wtq : (z == 1) ? wtk : wtv;
  const float* bias = (z == 0) ? bq : (z == 1) ? bk : bv;
  void* out = (z == 0) ? (void*)qb : (z == 1) ? (void*)kbh : (void*)vA;
  int mode = (z == 0) ? 0 : (z == 1) ? 3 : 4;
  gemm_body(A, Bt, bias, out, nullptr, NN, mode, (z == 0) ? qscale : 1.f,
            blockIdx.x, blockIdx.y);
}

// ------------------------------------------------------------- mean shift ----
// r0 shell (512 thr, 8 head-waves, dbuf staging) with transpose-free PV:
// the score MFMA's C-fragment (row=key=quad*4+r, col=query) IS the B-fragment
// of mfma_f32_16x16x16f16, so P feeds the sum/PV MFMAs from registers.
// s_p LDS round-trip (ds_write + lgkm wait + ds_read) eliminated entirely.
__device__ __forceinline__ void stage_tile(int h, int lane, int qt, int kt2,
                                           const h16* __restrict__ dynT3,
                                           const h16* __restrict__ kaug,
                                           const h16* __restrict__ xzT3,
                                           h16* bdy, h16* bka, h16* bxz) {
  if (h < 2)
    async16(dynT3 + (((size_t)qt * NKT2 + kt2) << 10) + h * 512, bdy + h * 512, lane);
  else if (h < 4)
    async16(kaug + ((size_t)kt2 << 10) + (h - 2) * 512, bka + (h - 2) * 512, lane);
  else if (h < 6)
    async16(xzT3 + ((size_t)kt2 << 10) + (h - 4) * 512, bxz + (h - 4) * 512, lane);
}

__device__ __forceinline__ void ldkf(const h16* __restrict__ kbh_h, int k0,
                                     int col, int quad, half8 kf[4]) {
  #pragma unroll
  for (int f = 0; f < 4; ++f)
    kf[f] = *(const half8*)(kbh_h + (size_t)(k0 + f * 16 + col) * 32 + quad * 8);
}

template <int LAST>
__device__ __forceinline__ void ms_compute(
    const h16* __restrict__ bdy, const h16* __restrict__ bka,
    const h16* __restrict__ bxz, const half8 kf[4], half8 qaf, half8 qf,
    const h16* __restrict__ vA0, int lane, int col, int quad,
    f32x4& accS, f32x4& fc0, f32x4& fc1) {
  half8 kz = {};
  half8 dv0 = *(const half8*)(bdy + lane * 8);
  half8 dv1 = *(const half8*)(bdy + 512 + lane * 8);
  #pragma unroll
  for (int f = 0; f < 4; ++f) {
    half8 ka = (quad < 2) ? *(const half8*)(bka + (f * 16 + col) * 16 + quad * 8) : kz;
    half8 dv = (f & 2) ? dv1 : dv0;
    f32x4 cc;
    #pragma unroll
    for (int r = 0; r < 4; ++r) cc[r] = (float)dv[(f & 1) * 4 + r];
    f32x4 g = __builtin_amdgcn_mfma_f32_16x16x32_f16(ka, qaf, cc, 0, 0, 0);
    f32x4 s = __builtin_amdgcn_mfma_f32_16x16x32_f16(kf[f], qf, g, 0, 0, 0);
    half4 pv;
    #pragma unroll
    for (int r = 0; r < 4; ++r) pv[r] = (h16)EXP2(s[r]);
    half4 xa = *(const half4*)(bxz + f * 256 + lane * 4);
    accS = MFMA16(xa, pv, accS);
    if (LAST) {
      half4 v0 = *(const half4*)(vA0 + f * 256 + lane * 4);
      half4 v1 = *(const half4*)(vA0 + VHALF + f * 256 + lane * 4);
      fc0 = MFMA16(v0, pv, fc0);
      fc1 = MFMA16(v1, pv, fc1);
    }
  }
}

template <int LAST>
__global__ __launch_bounds__(512, 4) void k_msattn(
    const h16* __restrict__ qb, const h16* __restrict__ kbh,
    const h16* __restrict__ vA, const h16* __restrict__ dynT3,
    const h16* __restrict__ qaug, const h16* __restrict__ kaug,
    const h16* __restrict__ xzT3, float* __restrict__ den_s,
    float* __restrict__ axh_s, float* __restrict__ axl_s,
    float* __restrict__ numT) {
  __shared__ h16 s_dy[2][1024];
  __shared__ h16 s_ka[2][1024];
  __shared__ h16 s_xz[2][1024];
  const int tid = threadIdx.x;
  const int h = tid >> 6;
  const int lane = tid & 63;
  const int col = lane & 15;
  const int quad = lane >> 4;
  const int qt = blockIdx.x;
  const int q0 = qt * 16;
  const int tb = blockIdx.y * KT;

  half8 kz = {};
  half8 qf = *(const half8*)(qb + (size_t)(q0 + col) * DD + h * 32 + quad * 8);
  half8 qaf = (quad < 2) ? *(const half8*)(qaug + (size_t)(q0 + col) * 16 + quad * 8) : kz;
  const h16* kbh_h = kbh + (size_t)h * NN * 32;
  const h16* vb = vA + (size_t)h * 2 * (NN / 16) * 256;   // head base
  f32x4 accS = (f32x4){0.f, 0.f, 0.f, 0.f};
  f32x4 fc0 = (f32x4){0.f, 0.f, 0.f, 0.f};
  f32x4 fc1 = (f32x4){0.f, 0.f, 0.f, 0.f};
  half8 kfA[4], kfB[4];

  stage_tile(h, lane, qt, tb, dynT3, kaug, xzT3, s_dy[0], s_ka[0], s_xz[0]);
  ldkf(kbh_h, tb * 64, col, quad, kfA);
  __syncthreads();          // drains async stage + kfA
  #pragma unroll 1
  for (int kt = 0; kt < KT; kt += 2) {
    int t1 = tb + kt + 1;
    stage_tile(h, lane, qt, t1, dynT3, kaug, xzT3, s_dy[1], s_ka[1], s_xz[1]);
    ldkf(kbh_h, t1 * 64, col, quad, kfB);
    ms_compute<LAST>(s_dy[0], s_ka[0], s_xz[0], kfA, qaf, qf,
                     vb + (size_t)(tb + kt) * 1024,
                     lane, col, quad, accS, fc0, fc1);
    __syncthreads();        // buf1 + kfB now resident
    int t2 = (kt + 2 < KT) ? tb + kt + 2 : t1;
    if (kt + 2 < KT)
      stage_tile(h, lane, qt, t2, dynT3, kaug, xzT3, s_dy[0], s_ka[0], s_xz[0]);
    ldkf(kbh_h, t2 * 64, col, quad, kfA);
    ms_compute<LAST>(s_dy[1], s_ka[1], s_xz[1], kfB, qaf, qf,
                     vb + (size_t)t1 * 1024,
                     lane, col, quad, accS, fc0, fc1);
    __syncthreads();
  }

  // accS D rows: 0=den, 1-3=num_hi, 4-6=num_lo
  int q = q0 + col;
  size_t sidx = (size_t)(blockIdx.y * NH + h) * NN + q;
  if (quad == 0) {
    den_s[sidx] = accS[0];
    axh_s[sidx * 3 + 0] = accS[1];
    axh_s[sidx * 3 + 1] = accS[2];
    axh_s[sidx * 3 + 2] = accS[3];
  } else if (quad == 1) {
    axl_s[sidx * 3 + 0] = accS[0];
    axl_s[sidx * 3 + 1] = accS[1];
    axl_s[sidx * 3 + 2] = accS[2];
  }
  if (LAST) {
    #pragma unroll
    for (int r = 0; r < 4; ++r) {
      atomicAdd(&numT[(size_t)(h * 32 + quad * 4 + r) * NN + q], fc0[r]);
      atomicAdd(&numT[(size_t)(h * 32 + 16 + quad * 4 + r) * NN + q], fc1[r]);
    }
  }
}

// ---------------------------------------------------------------- combine ----
__global__ __launch_bounds__(256) void k_combine(
    const float* __restrict__ den_s, const float* __restrict__ axh_s,
    const float* __restrict__ axl_s, float* __restrict__ den_tot,
    h16* __restrict__ qaug, h16* __restrict__ kaug, h16* __restrict__ xzT3,
    float* __restrict__ out3) {
  int q = blockIdx.x * 256 + threadIdx.x;
  if (q >= NN) return;
  float X = 0.f, Y = 0.f, Z = 0.f;
  #pragma unroll
  for (int h = 0; h < NH; ++h) {
    float d = 0.f, x = 0.f, y = 0.f, z = 0.f;
    #pragma unroll
    for (int s = 0; s < SPLIT; ++s) {
      size_t idx = (size_t)(s * NH + h) * NN + q;
      d += den_s[idx];
      x += axh_s[idx * 3 + 0] + axl_s[idx * 3 + 0];
      y += axh_s[idx * 3 + 1] + axl_s[idx * 3 + 1];
      z += axh_s[idx * 3 + 2] + axl_s[idx * 3 + 2];
    }
    den_tot[h * NN + q] = d;
    float inv = 0.125f / d;
    X = fmaf(x, inv, X);
    Y = fmaf(y, inv, Y);
    Z = fmaf(z, inv, Z);
  }
  if (out3) {
    out3[q * 3 + 0] = X;
    out3[q * 3 + 1] = Y;
    out3[q * 3 + 2] = Z;
  } else {
    write_aug(q, X, Y, Z, qaug, kaug, xzT3);
  }
}

// ----------------------------------------------------------------- finish ----
__global__ __launch_bounds__(256) void k_finish(
    const float* __restrict__ numT, const float* __restrict__ den_tot,
    h16* __restrict__ featb) {
  __shared__ float tile[32][33];
  int q0 = blockIdx.x * 32, d0 = blockIdx.y * 32;
  int tx = threadIdx.x & 31, ty = threadIdx.x >> 5;   // 32 x 8
  #pragma unroll
  for (int i = 0; i < 4; ++i)
    tile[ty + i * 8][tx] = numT[(size_t)(d0 + ty + i * 8) * NN + q0 + tx];
  __syncthreads();
  int h = d0 >> 5;
  #pragma unroll
  for (int i = 0; i < 4; ++i) {
    int q = q0 + ty + i * 8;
    float inv = 1.f / den_tot[h * NN + q];
    featb[(size_t)q * DD + d0 + tx] = (h16)(tile[tx][ty + i * 8] * inv);
  }
}

// ----------------------------------------------------------------- launch ----
extern "C" void kernel_launch(void* const* d_in, const int* in_sizes, int n_in,
                              void* d_out, int out_size, void* d_ws, size_t ws_size,
                              hipStream_t stream) {
  const float* x   = (const float*)d_in[0];
  const float* xyz = (const float*)d_in[1];
  const float* dy  = (const float*)d_in[2];
  const int* dm    = (const int*)d_in[3];
  const int* bim   = (const int*)d_in[4];
  const float* Wq = (const float*)d_in[5];
  const float* bq = (const float*)d_in[6];
  const float* Wk = (const float*)d_in[7];
  const float* bk = (const float*)d_in[8];
  const float* Wv = (const float*)d_in[9];
  const float* bv = (const float*)d_in[10];
  const float* Wo = (const float*)d_in[11];
  const float* bo = (const float*)d_in[12];

  char* p = (char*)d_ws;
  h16* xb  = (h16*)p; p += (size_t)NN * DD * 2;
  h16* wtq = (h16*)p; p += 256 * 256 * 2;
  h16* wtk = (h16*)p; p += 256 * 256 * 2;
  h16* wtv = (h16*)p; p += 256 * 256 * 2;
  h16* wto = (h16*)p; p += 256 * 256 * 2;
  h16* qb    = (h16*)p; p += (size_t)NN * DD * 2;
  h16* kbh   = (h16*)p; p += (size_t)NN * DD * 2;
  h16* vA    = (h16*)p; p += (size_t)NN * DD * 2;
  h16* featb = (h16*)p; p += (size_t)NN * DD * 2;
  h16* dynT3 = (h16*)p; p += (size_t)NN * NN * 2;
  h16* qaug  = (h16*)p; p += (size_t)NN * 16 * 2;
  h16* kaug  = (h16*)p; p += (size_t)NN * 16 * 2;
  h16* xzT3  = (h16*)p; p += (size_t)NKT2 * 1024 * 2;
  float* den_s = (float*)p; p += (size_t)SPLIT * NH * NN * 4;
  float* axh_s = (float*)p; p += (size_t)SPLIT * NH * NN * 3 * 4;
  float* axl_s = (float*)p; p += (size_t)SPLIT * NH * NN * 3 * 4;
  float* den_tot = (float*)p; p += (size_t)NH * NN * 4;
  float* numT = (float*)p; p += (size_t)DD * NN * 4;

  hipMemsetAsync(numT, 0, (size_t)DD * NN * 4, stream);
  k_convert<<<(NN * DD + NN + 255) / 256, 256, 0, stream>>>(x, xyz, xb, qaug,
                                                            kaug, xzT3);
  k_wt<<<dim3(8, 8, 4), 256, 0, stream>>>(Wq, Wk, Wv, Wo, wtq, wtk, wtv, wto);
  k_prep<<<dim3(3, 192), 256, 0, stream>>>(dy, dm, bim, dynT3);
  k_gemm3<<<dim3(96, 4, 3), 256, 0, stream>>>(xb, wtq, wtk, wtv, bq, bk, bv,
                                              qb, kbh, vA,
                                              0.17677669529663689f * LN2INV);

  float* xyz_final = (float*)d_out;            // output 0: [3072,3]
  float* out_final = (float*)d_out + NN * 3;   // output 1: [3072,256]

  k_msattn<0><<<dim3(NN / 16, SPLIT), 512, 0, stream>>>(
      qb, kbh, vA, dynT3, qaug, kaug, xzT3, den_s, axh_s, axl_s, nullptr);
  k_combine<<<12, 256, 0, stream>>>(den_s, axh_s, axl_s, den_tot,
                                    qaug, kaug, xzT3, nullptr);
  k_msattn<0><<<dim3(NN / 16, SPLIT), 512, 0, stream>>>(
      qb, kbh, vA, dynT3, qaug, kaug, xzT3, den_s, axh_s, axl_s, nullptr);
  k_combine<<<12, 256, 0, stream>>>(den_s, axh_s, axl_s, den_tot,
                                    qaug, kaug, xzT3, nullptr);
  k_msattn<1><<<dim3(NN / 16, SPLIT), 512, 0, stream>>>(
      qb, kbh, vA, dynT3, qaug, kaug, xzT3, den_s, axh_s, axl_s, numT);
  k_combine<<<12, 256, 0, stream>>>(den_s, axh_s, axl_s, den_tot,
                                    nullptr, nullptr, nullptr, xyz_final);
  k_finish<<<dim3(96, 8), 256, 0, stream>>>(numT, den_tot, featb);
  k_gemm<<<dim3(96, 4), 256, 0, stream>>>(featb, wto, bo, out_final, x, NN, 2, 1.f);
}

// Round 8
// 324.948 us; speedup vs baseline: 1.2171x; 1.1487x over previous
//
#include <hip/hip_runtime.h>
#include <hip/hip_fp16.h>

#define NN 3072
#define DD 256
#define NH 8
#define SPLIT 4
#define KT (NN / SPLIT / 64)   // 12 key-tiles of 64 per split
#define NKT2 (NN / 64)         // 48 global key tiles
#define VHALF ((NN / 16) * 256)   // 49152: stride between v-dim halves
#define LN2INV 1.4426950408889634f

typedef _Float16 h16;
typedef __attribute__((ext_vector_type(4))) _Float16 half4;
typedef __attribute__((ext_vector_type(8))) _Float16 half8;
typedef __attribute__((ext_vector_type(4))) float f32x4;

#if __has_builtin(__builtin_amdgcn_exp2f)
#define EXP2(x) __builtin_amdgcn_exp2f(x)
#else
#define EXP2(x) __expf((x) * 0.69314718056f)
#endif

// K=16 f16 MFMA (legacy naming: no underscore before f16 -- gfx950 keeps it).
// B-fragment layout (k=quad*4+j, n=lane&15) EXACTLY matches the C-fragment of
// the score MFMA -> P feeds PV/sum MFMAs straight from registers.
#define MFMA16(a, b, c) __builtin_amdgcn_mfma_f32_16x16x16f16(a, b, c, 0, 0, 0)

// --------------------------------------------------------- async 16B stage ---
__device__ __forceinline__ void async16(const h16* g, h16* l, int lane) {
#if __has_builtin(__builtin_amdgcn_global_load_lds)
  __builtin_amdgcn_global_load_lds(
      (const __attribute__((address_space(1))) void*)(g + (size_t)lane * 8),
      (__attribute__((address_space(3))) void*)l, 16, 0, 0);
#else
  *(half8*)(l + lane * 8) = *(const half8*)(g + (size_t)lane * 8);
#endif
}

// ------------------------------------------------------------- aug writer ----
// qaug/kaug: 16-dim fp16 aug vectors (geo term via one MFMA, dims 12-15 zero).
// xzT3 layout: A-operand tiles for 16x16x16 MFMA.
// xzT3[kt2][f(4)][quad(4)][m(16)][j(4)]: comp[m] of key kt2*64+f*16+quad*4+j,
// comp = {1, xh, yh, zh, xl, yl, zl, 0...}.
__device__ inline void write_aug(int q, float x, float y, float z,
                                 h16* __restrict__ qaug, h16* __restrict__ kaug,
                                 h16* __restrict__ xzT3) {
  float sx = 0.5f * LN2INV * x, sy = 0.5f * LN2INV * y, sz = 0.5f * LN2INV * z;
  h16 shx = (h16)sx, shy = (h16)sy, shz = (h16)sz;
  h16 slx = (h16)(sx - (float)shx), sly = (h16)(sy - (float)shy), slz = (h16)(sz - (float)shz);
  h16 hx = (h16)x, hy = (h16)y, hz = (h16)z;
  h16 lx = (h16)(x - (float)hx), ly = (h16)(y - (float)hy), lz = (h16)(z - (float)hz);
  float n2n = -0.25f * LN2INV * (x * x + y * y + z * z);
  h16 nh = (h16)n2n, nl = (h16)(n2n - (float)nh);
  h16 qa[16], ka[16];
  #pragma unroll
  for (int i = 0; i < 16; ++i) { qa[i] = (h16)0.f; ka[i] = (h16)0.f; }
  qa[0] = shx; qa[1] = shy; qa[2] = shz;       // pairs A d0-2 = hk
  qa[3] = shx; qa[4] = shy; qa[5] = shz;       // pairs A d3-5 = lk
  qa[6] = slx; qa[7] = sly; qa[8] = slz;       // pairs A d6-8 = hk
  qa[9] = (h16)1.f; qa[10] = (h16)1.f;         // pairs key-norm hi/lo
  qa[11] = (h16)n2n;                           // query norm (row-const)
  ka[0] = hx; ka[1] = hy; ka[2] = hz;
  ka[3] = lx; ka[4] = ly; ka[5] = lz;
  ka[6] = hx; ka[7] = hy; ka[8] = hz;
  ka[9] = nh; ka[10] = nl;
  ka[11] = (h16)1.f;
  *(half8*)(qaug + (size_t)q * 16) = ((half8*)qa)[0];
  *(half8*)(qaug + (size_t)q * 16 + 8) = ((half8*)qa)[1];
  *(half8*)(kaug + (size_t)q * 16) = ((half8*)ka)[0];
  *(half8*)(kaug + (size_t)q * 16 + 8) = ((half8*)ka)[1];
  int kt2 = q >> 6, kk = q & 63;
  int f = kk >> 4, qd = (kk >> 2) & 3, j = kk & 3;
  h16* b = xzT3 + ((size_t)kt2 << 10) + f * 256 + qd * 64 + j;
  b[0] = (h16)1.f;
  b[4] = hx; b[8] = hy; b[12] = hz;
  b[16] = lx; b[20] = ly; b[24] = lz;
  #pragma unroll
  for (int m = 7; m < 16; ++m) b[m * 4] = (h16)0.f;
}

// ------------------------------------------------- convert + initial aug -----
// Also zeroes numT (exactly NN*DD floats, same index range as xb) -- removes
// the separate hipMemsetAsync dispatch.
__global__ __launch_bounds__(256) void k_convert(
    const float* __restrict__ x, const float* __restrict__ xyz,
    h16* __restrict__ xb, h16* __restrict__ qaug,
    h16* __restrict__ kaug, h16* __restrict__ xzT3,
    float* __restrict__ numT) {
  int t = blockIdx.x * 256 + threadIdx.x;
  const int NX = NN * DD;
  if (t < NX) { xb[t] = (h16)x[t]; numT[t] = 0.f; return; }
  int q = t - NX;
  if (q < NN) write_aug(q, xyz[q * 3], xyz[q * 3 + 1], xyz[q * 3 + 2], qaug, kaug, xzT3);
}

// --------------------------------------------------------- W transpose -------
__global__ __launch_bounds__(256) void k_wt(
    const float* __restrict__ Wq, const float* __restrict__ Wk,
    const float* __restrict__ Wv, const float* __restrict__ Wo,
    h16* __restrict__ wtq, h16* __restrict__ wtk, h16* __restrict__ wtv,
    h16* __restrict__ wto) {
  __shared__ float tile[32][33];
  int m = blockIdx.z;
  const float* W = (m == 0) ? Wq : (m == 1) ? Wk : (m == 2) ? Wv : Wo;
  h16* wt = (m == 0) ? wtq : (m == 1) ? wtk : (m == 2) ? wtv : wto;
  int n0 = blockIdx.x * 32, k0 = blockIdx.y * 32;
  int tx = threadIdx.x & 31, ty = threadIdx.x >> 5;   // 32 x 8
  #pragma unroll
  for (int i = 0; i < 4; ++i)
    tile[ty + i * 8][tx] = W[(size_t)(k0 + ty + i * 8) * 256 + n0 + tx];
  __syncthreads();
  #pragma unroll
  for (int i = 0; i < 4; ++i)
    wt[(size_t)(n0 + ty + i * 8) * 256 + k0 + tx] = (h16)tile[tx][ty + i * 8];
}

// ---------------------------------------------------------------- prep dy ----
// vec4 loads (48 independent loads/thread), bitwise mask, 1024-col blocks,
// coalesced half8 stores in MFMA C-fragment layout.
__global__ __launch_bounds__(256) void k_prep(
    const float* __restrict__ dy, const int* __restrict__ dm,
    const int* __restrict__ bim, h16* __restrict__ dynT3) {
  __shared__ h16 sv[16][1036];
  int qt = blockIdx.y;                 // 0..191  (16 query rows)
  int cb = blockIdx.x;                 // 0..2    (1024 key cols)
  int t = threadIdx.x;
  int c0 = cb * 1024 + t * 4;
  #pragma unroll
  for (int r = 0; r < 16; ++r) {
    int row = qt * 16 + r;
    size_t idx = (size_t)row * NN + c0;
    int4 m4 = *(const int4*)(dm + idx);
    int4 b4 = *(const int4*)(bim + idx);
    float4 d4 = *(const float4*)(dy + idx);
    h16* s = &sv[r][t * 4];
    int mm[4] = {m4.x & b4.x, m4.y & b4.y, m4.z & b4.z, m4.w & b4.w};
    float dd[4] = {d4.x, d4.y, d4.z, d4.w};
    #pragma unroll
    for (int j = 0; j < 4; ++j) {
      bool diag = (row == c0 + j);
      bool valid = (mm[j] != 0) | diag;
      s[j] = (h16)(valid ? (-LN2INV * (dd[j] + (diag ? 2.5e-5f : 0.f))) : -43281.f);
    }
  }
  __syncthreads();
  #pragma unroll
  for (int s2 = 0; s2 < 8; ++s2) {
    int s = t + s2 * 256;              // 0..2047 : 16 tiles x 128 half8 slots
    int tile = s >> 7;
    int sl = s & 127;                  // chunk*64 + lane
    int chunk = sl >> 6;
    int lane = sl & 63;
    int row = lane & 15, quad = lane >> 4;
    int base = tile * 64 + chunk * 32 + quad * 4;
    half4 lo = *(const half4*)&sv[row][base];
    half4 hi = *(const half4*)&sv[row][base + 16];
    half8 o;
    #pragma unroll
    for (int j = 0; j < 4; ++j) { o[j] = lo[j]; o[j + 4] = hi[j]; }
    h16* dst = dynT3 + (((size_t)qt * NKT2 + (cb * 16 + tile)) << 10) + sl * 8;
    *(half8*)dst = o;
  }
}

// ------------------------------------------------------------------- gemm ----
// mode 0: fp16 row-major *scale; mode 2: fp32 +resid;
// mode 3: fp16 per-head contiguous kbh[h][token][32];
// mode 4: fp16 MFMA-A-layout vA[h*2+half][tile(192)][quad(4)][dim(16)][j(4)]
__device__ inline void gemm_body(const h16* __restrict__ A, const h16* __restrict__ Bt,
                                 const float* __restrict__ bias, void* __restrict__ out,
                                 const float* __restrict__ resid, int M, int mode,
                                 float scale, int bx, int by) {
  int lane = threadIdx.x & 63;
  int wave = threadIdx.x >> 6;
  int col = lane & 15, quad = lane >> 4;
  int m0 = bx * 32;
  int n0 = by * 64 + wave * 16;
  f32x4 acc[2];
  acc[0] = (f32x4){0.f, 0.f, 0.f, 0.f};
  acc[1] = (f32x4){0.f, 0.f, 0.f, 0.f};
  #pragma unroll
  for (int kk = 0; kk < DD; kk += 32) {
    half8 b = *(const half8*)(Bt + (size_t)(n0 + col) * DD + kk + quad * 8);
    #pragma unroll
    for (int mr = 0; mr < 2; ++mr) {
      half8 a = *(const half8*)(A + (size_t)(m0 + mr * 16 + col) * DD + kk + quad * 8);
      acc[mr] = __builtin_amdgcn_mfma_f32_16x16x32_f16(a, b, acc[mr], 0, 0, 0);
    }
  }
  float bb = bias[n0 + col];
  #pragma unroll
  for (int mr = 0; mr < 2; ++mr) {
    #pragma unroll
    for (int r = 0; r < 4; ++r) {
      int m = m0 + mr * 16 + quad * 4 + r;
      int n = n0 + col;
      float v = acc[mr][r] + bb;
      if (mode == 0)      ((h16*)out)[(size_t)m * DD + n] = (h16)(v * scale);
      else if (mode == 3) ((h16*)out)[((size_t)(n >> 5) * NN + m) * 32 + (n & 31)] = (h16)v;
      else if (mode == 4) {
        int hh = n >> 5, d = n & 31;
        size_t a = ((((size_t)hh * 2 + (d >> 4)) * (NN / 16) + (m >> 4)) * 64 +
                    ((m >> 2) & 3) * 16 + (d & 15)) * 4 + (m & 3);
        ((h16*)out)[a] = (h16)v;
      }
      else ((float*)out)[(size_t)m * DD + n] = v + resid[(size_t)m * DD + n];
    }
  }
}

__global__ __launch_bounds__(256) void k_gemm(
    const h16* __restrict__ A, const h16* __restrict__ Bt,
    const float* __restrict__ bias, void* __restrict__ out,
    const float* __restrict__ resid, int M, int mode, float scale) {
  gemm_body(A, Bt, bias, out, resid, M, mode, scale, blockIdx.x, blockIdx.y);
}

__global__ __launch_bounds__(256) void k_gemm3(
    const h16* __restrict__ A, const h16* __restrict__ wtq,
    const h16* __restrict__ wtk, const h16* __restrict__ wtv,
    const float* __restrict__ bq, const float* __restrict__ bk,
    const float* __restrict__ bv, h16* __restrict__ qb, h16* __restrict__ kbh,
    h16* __restrict__ vA, float qscale) {
  int z = blockIdx.z;
  const h16* Bt = (z == 0) ? wtq : (z == 1) ? wtk : wtv;
  const float* bias = (z == 0) ? bq : (z == 1) ? bk : bv;
  void* out = (z == 0) ? (void*)qb : (z == 1) ? (void*)kbh : (void*)vA;
  int mode = (z == 0) ? 0 : (z == 1) ? 3 : 4;
  gemm_body(A, Bt, bias, out, nullptr, NN, mode, (z == 0) ? qscale : 1.f,
            blockIdx.x, blockIdx.y);
}

// ------------------------------------------------------------- mean shift ----
// r7 structure (transpose-free PV, no s_p) + s_setprio around the MFMA/exp2
// cluster (T5: favors compute-phase waves when 24 waves/CU share the SIMDs).
__device__ __forceinline__ void stage_tile(int h, int lane, int qt, int kt2,
                                           const h16* __restrict__ dynT3,
                                           const h16* __restrict__ kaug,
                                           const h16* __restrict__ xzT3,
                                           h16* bdy, h16* bka, h16* bxz) {
  if (h < 2)
    async16(dynT3 + (((size_t)qt * NKT2 + kt2) << 10) + h * 512, bdy + h * 512, lane);
  else if (h < 4)
    async16(kaug + ((size_t)kt2 << 10) + (h - 2) * 512, bka + (h - 2) * 512, lane);
  else if (h < 6)
    async16(xzT3 + ((size_t)kt2 << 10) + (h - 4) * 512, bxz + (h - 4) * 512, lane);
}

__device__ __forceinline__ void ldkf(const h16* __restrict__ kbh_h, int k0,
                                     int col, int quad, half8 kf[4]) {
  #pragma unroll
  for (int f = 0; f < 4; ++f)
    kf[f] = *(const half8*)(kbh_h + (size_t)(k0 + f * 16 + col) * 32 + quad * 8);
}

template <int LAST>
__device__ __forceinline__ void ms_compute(
    const h16* __restrict__ bdy, const h16* __restrict__ bka,
    const h16* __restrict__ bxz, const half8 kf[4], half8 qaf, half8 qf,
    const h16* __restrict__ vA0, int lane, int col, int quad,
    f32x4& accS, f32x4& fc0, f32x4& fc1) {
  half8 kz = {};
  half8 dv0 = *(const half8*)(bdy + lane * 8);
  half8 dv1 = *(const half8*)(bdy + 512 + lane * 8);
  half4 xa[4];
  #pragma unroll
  for (int f = 0; f < 4; ++f)
    xa[f] = *(const half4*)(bxz + f * 256 + lane * 4);
  __builtin_amdgcn_s_setprio(1);
  #pragma unroll
  for (int f = 0; f < 4; ++f) {
    half8 ka = (quad < 2) ? *(const half8*)(bka + (f * 16 + col) * 16 + quad * 8) : kz;
    half8 dv = (f & 2) ? dv1 : dv0;
    f32x4 cc;
    #pragma unroll
    for (int r = 0; r < 4; ++r) cc[r] = (float)dv[(f & 1) * 4 + r];
    f32x4 g = __builtin_amdgcn_mfma_f32_16x16x32_f16(ka, qaf, cc, 0, 0, 0);
    f32x4 s = __builtin_amdgcn_mfma_f32_16x16x32_f16(kf[f], qf, g, 0, 0, 0);
    half4 pv;
    #pragma unroll
    for (int r = 0; r < 4; ++r) pv[r] = (h16)EXP2(s[r]);
    accS = MFMA16(xa[f], pv, accS);
    if (LAST) {
      half4 v0 = *(const half4*)(vA0 + f * 256 + lane * 4);
      half4 v1 = *(const half4*)(vA0 + VHALF + f * 256 + lane * 4);
      fc0 = MFMA16(v0, pv, fc0);
      fc1 = MFMA16(v1, pv, fc1);
    }
  }
  __builtin_amdgcn_s_setprio(0);
}

template <int LAST>
__global__ __launch_bounds__(512, 4) void k_msattn(
    const h16* __restrict__ qb, const h16* __restrict__ kbh,
    const h16* __restrict__ vA, const h16* __restrict__ dynT3,
    const h16* __restrict__ qaug, const h16* __restrict__ kaug,
    const h16* __restrict__ xzT3, float* __restrict__ den_s,
    float* __restrict__ axh_s, float* __restrict__ axl_s,
    float* __restrict__ numT) {
  __shared__ h16 s_dy[2][1024];
  __shared__ h16 s_ka[2][1024];
  __shared__ h16 s_xz[2][1024];
  const int tid = threadIdx.x;
  const int h = tid >> 6;
  const int lane = tid & 63;
  const int col = lane & 15;
  const int quad = lane >> 4;
  const int qt = blockIdx.x;
  const int q0 = qt * 16;
  const int tb = blockIdx.y * KT;

  half8 kz = {};
  half8 qf = *(const half8*)(qb + (size_t)(q0 + col) * DD + h * 32 + quad * 8);
  half8 qaf = (quad < 2) ? *(const half8*)(qaug + (size_t)(q0 + col) * 16 + quad * 8) : kz;
  const h16* kbh_h = kbh + (size_t)h * NN * 32;
  const h16* vb = vA + (size_t)h * 2 * (NN / 16) * 256;   // head base
  f32x4 accS = (f32x4){0.f, 0.f, 0.f, 0.f};
  f32x4 fc0 = (f32x4){0.f, 0.f, 0.f, 0.f};
  f32x4 fc1 = (f32x4){0.f, 0.f, 0.f, 0.f};
  half8 kfA[4], kfB[4];

  stage_tile(h, lane, qt, tb, dynT3, kaug, xzT3, s_dy[0], s_ka[0], s_xz[0]);
  ldkf(kbh_h, tb * 64, col, quad, kfA);
  __syncthreads();          // drains async stage + kfA
  #pragma unroll 1
  for (int kt = 0; kt < KT; kt += 2) {
    int t1 = tb + kt + 1;
    stage_tile(h, lane, qt, t1, dynT3, kaug, xzT3, s_dy[1], s_ka[1], s_xz[1]);
    ldkf(kbh_h, t1 * 64, col, quad, kfB);
    ms_compute<LAST>(s_dy[0], s_ka[0], s_xz[0], kfA, qaf, qf,
                     vb + (size_t)(tb + kt) * 1024,
                     lane, col, quad, accS, fc0, fc1);
    __syncthreads();        // buf1 + kfB now resident
    int t2 = (kt + 2 < KT) ? tb + kt + 2 : t1;
    if (kt + 2 < KT)
      stage_tile(h, lane, qt, t2, dynT3, kaug, xzT3, s_dy[0], s_ka[0], s_xz[0]);
    ldkf(kbh_h, t2 * 64, col, quad, kfA);
    ms_compute<LAST>(s_dy[1], s_ka[1], s_xz[1], kfB, qaf, qf,
                     vb + (size_t)t1 * 1024,
                     lane, col, quad, accS, fc0, fc1);
    __syncthreads();
  }

  // accS D rows: 0=den, 1-3=num_hi, 4-6=num_lo
  int q = q0 + col;
  size_t sidx = (size_t)(blockIdx.y * NH + h) * NN + q;
  if (quad == 0) {
    den_s[sidx] = accS[0];
    axh_s[sidx * 3 + 0] = accS[1];
    axh_s[sidx * 3 + 1] = accS[2];
    axh_s[sidx * 3 + 2] = accS[3];
  } else if (quad == 1) {
    axl_s[sidx * 3 + 0] = accS[0];
    axl_s[sidx * 3 + 1] = accS[1];
    axl_s[sidx * 3 + 2] = accS[2];
  }
  if (LAST) {
    #pragma unroll
    for (int r = 0; r < 4; ++r) {
      atomicAdd(&numT[(size_t)(h * 32 + quad * 4 + r) * NN + q], fc0[r]);
      atomicAdd(&numT[(size_t)(h * 32 + 16 + quad * 4 + r) * NN + q], fc1[r]);
    }
  }
}

// ---------------------------------------------------------------- combine ----
// Parallel version: 96 blocks x (32 q x 8 h) threads; per-thread 4-split sum,
// then width-8 shfl_xor reduction over heads. Old version: 12 blocks, 224
// serial loads/thread on a ~95%-idle GPU.
__global__ __launch_bounds__(256) void k_combine(
    const float* __restrict__ den_s, const float* __restrict__ axh_s,
    const float* __restrict__ axl_s, float* __restrict__ den_tot,
    h16* __restrict__ qaug, h16* __restrict__ kaug, h16* __restrict__ xzT3,
    float* __restrict__ out3) {
  int h = threadIdx.x & 7;
  int q = blockIdx.x * 32 + (threadIdx.x >> 3);
  float d = 0.f, x = 0.f, y = 0.f, z = 0.f;
  #pragma unroll
  for (int s = 0; s < SPLIT; ++s) {
    size_t idx = (size_t)(s * NH + h) * NN + q;
    d += den_s[idx];
    x += axh_s[idx * 3 + 0] + axl_s[idx * 3 + 0];
    y += axh_s[idx * 3 + 1] + axl_s[idx * 3 + 1];
    z += axh_s[idx * 3 + 2] + axl_s[idx * 3 + 2];
  }
  den_tot[h * NN + q] = d;
  float inv = 0.125f / d;
  float X = x * inv, Y = y * inv, Z = z * inv;
  #pragma unroll
  for (int m = 1; m < 8; m <<= 1) {
    X += __shfl_xor(X, m);
    Y += __shfl_xor(Y, m);
    Z += __shfl_xor(Z, m);
  }
  if (h == 0) {
    if (out3) {
      out3[q * 3 + 0] = X;
      out3[q * 3 + 1] = Y;
      out3[q * 3 + 2] = Z;
    } else {
      write_aug(q, X, Y, Z, qaug, kaug, xzT3);
    }
  }
}

// ----------------------------------------------------------------- finish ----
__global__ __launch_bounds__(256) void k_finish(
    const float* __restrict__ numT, const float* __restrict__ den_tot,
    h16* __restrict__ featb) {
  __shared__ float tile[32][33];
  int q0 = blockIdx.x * 32, d0 = blockIdx.y * 32;
  int tx = threadIdx.x & 31, ty = threadIdx.x >> 5;   // 32 x 8
  #pragma unroll
  for (int i = 0; i < 4; ++i)
    tile[ty + i * 8][tx] = numT[(size_t)(d0 + ty + i * 8) * NN + q0 + tx];
  __syncthreads();
  int h = d0 >> 5;
  #pragma unroll
  for (int i = 0; i < 4; ++i) {
    int q = q0 + ty + i * 8;
    float inv = 1.f / den_tot[h * NN + q];
    featb[(size_t)q * DD + d0 + tx] = (h16)(tile[tx][ty + i * 8] * inv);
  }
}

// ----------------------------------------------------------------- launch ----
extern "C" void kernel_launch(void* const* d_in, const int* in_sizes, int n_in,
                              void* d_out, int out_size, void* d_ws, size_t ws_size,
                              hipStream_t stream) {
  const float* x   = (const float*)d_in[0];
  const float* xyz = (const float*)d_in[1];
  const float* dy  = (const float*)d_in[2];
  const int* dm    = (const int*)d_in[3];
  const int* bim   = (const int*)d_in[4];
  const float* Wq = (const float*)d_in[5];
  const float* bq = (const float*)d_in[6];
  const float* Wk = (const float*)d_in[7];
  const float* bk = (const float*)d_in[8];
  const float* Wv = (const float*)d_in[9];
  const float* bv = (const float*)d_in[10];
  const float* Wo = (const float*)d_in[11];
  const float* bo = (const float*)d_in[12];

  char* p = (char*)d_ws;
  h16* xb  = (h16*)p; p += (size_t)NN * DD * 2;
  h16* wtq = (h16*)p; p += 256 * 256 * 2;
  h16* wtk = (h16*)p; p += 256 * 256 * 2;
  h16* wtv = (h16*)p; p += 256 * 256 * 2;
  h16* wto = (h16*)p; p += 256 * 256 * 2;
  h16* qb    = (h16*)p; p += (size_t)NN * DD * 2;
  h16* kbh   = (h16*)p; p += (size_t)NN * DD * 2;
  h16* vA    = (h16*)p; p += (size_t)NN * DD * 2;
  h16* featb = (h16*)p; p += (size_t)NN * DD * 2;
  h16* dynT3 = (h16*)p; p += (size_t)NN * NN * 2;
  h16* qaug  = (h16*)p; p += (size_t)NN * 16 * 2;
  h16* kaug  = (h16*)p; p += (size_t)NN * 16 * 2;
  h16* xzT3  = (h16*)p; p += (size_t)NKT2 * 1024 * 2;
  float* den_s = (float*)p; p += (size_t)SPLIT * NH * NN * 4;
  float* axh_s = (float*)p; p += (size_t)SPLIT * NH * NN * 3 * 4;
  float* axl_s = (float*)p; p += (size_t)SPLIT * NH * NN * 3 * 4;
  float* den_tot = (float*)p; p += (size_t)NH * NN * 4;
  float* numT = (float*)p; p += (size_t)DD * NN * 4;

  k_convert<<<(NN * DD + NN + 255) / 256, 256, 0, stream>>>(x, xyz, xb, qaug,
                                                            kaug, xzT3, numT);
  k_wt<<<dim3(8, 8, 4), 256, 0, stream>>>(Wq, Wk, Wv, Wo, wtq, wtk, wtv, wto);
  k_prep<<<dim3(3, 192), 256, 0, stream>>>(dy, dm, bim, dynT3);
  k_gemm3<<<dim3(96, 4, 3), 256, 0, stream>>>(xb, wtq, wtk, wtv, bq, bk, bv,
                                              qb, kbh, vA,
                                              0.17677669529663689f * LN2INV);

  float* xyz_final = (float*)d_out;            // output 0: [3072,3]
  float* out_final = (float*)d_out + NN * 3;   // output 1: [3072,256]

  k_msattn<0><<<dim3(NN / 16, SPLIT), 512, 0, stream>>>(
      qb, kbh, vA, dynT3, qaug, kaug, xzT3, den_s, axh_s, axl_s, nullptr);
  k_combine<<<96, 256, 0, stream>>>(den_s, axh_s, axl_s, den_tot,
                                    qaug, kaug, xzT3, nullptr);
  k_msattn<0><<<dim3(NN / 16, SPLIT), 512, 0, stream>>>(
      qb, kbh, vA, dynT3, qaug, kaug, xzT3, den_s, axh_s, axl_s, nullptr);
  k_combine<<<96, 256, 0, stream>>>(den_s, axh_s, axl_s, den_tot,
                                    qaug, kaug, xzT3, nullptr);
  k_msattn<1><<<dim3(NN / 16, SPLIT), 512, 0, stream>>>(
      qb, kbh, vA, dynT3, qaug, kaug, xzT3, den_s, axh_s, axl_s, numT);
  k_combine<<<96, 256, 0, stream>>>(den_s, axh_s, axl_s, den_tot,
                                    nullptr, nullptr, nullptr, xyz_final);
  k_finish<<<dim3(96, 8), 256, 0, stream>>>(numT, den_tot, featb);
  k_gemm<<<dim3(96, 4), 256, 0, stream>>>(featb, wto, bo, out_final, x, NN, 2, 1.f);
}

// Round 9
// 320.306 us; speedup vs baseline: 1.2348x; 1.0145x over previous
//
#include <hip/hip_runtime.h>
#include <hip/hip_fp16.h>

#define NN 3072
#define DD 256
#define NH 8
#define SPLIT 4
#define KT (NN / SPLIT / 64)   // 12 key-tiles of 64 per split
#define NKT2 (NN / 64)         // 48 global key tiles
#define VHALF ((NN / 16) * 256)   // 49152: stride between v-dim halves
#define LN2INV 1.4426950408889634f

typedef _Float16 h16;
typedef __attribute__((ext_vector_type(4))) _Float16 half4;
typedef __attribute__((ext_vector_type(8))) _Float16 half8;
typedef __attribute__((ext_vector_type(4))) float f32x4;

#if __has_builtin(__builtin_amdgcn_exp2f)
#define EXP2(x) __builtin_amdgcn_exp2f(x)
#else
#define EXP2(x) __expf((x) * 0.69314718056f)
#endif

// K=16 f16 MFMA (legacy naming: no underscore before f16 -- gfx950 keeps it).
// B-fragment layout (k=quad*4+j, n=lane&15) EXACTLY matches the C-fragment of
// the score MFMA -> P feeds PV/sum MFMAs straight from registers.
#define MFMA16(a, b, c) __builtin_amdgcn_mfma_f32_16x16x16f16(a, b, c, 0, 0, 0)

// --------------------------------------------------------- async 16B stage ---
__device__ __forceinline__ void async16(const h16* g, h16* l, int lane) {
#if __has_builtin(__builtin_amdgcn_global_load_lds)
  __builtin_amdgcn_global_load_lds(
      (const __attribute__((address_space(1))) void*)(g + (size_t)lane * 8),
      (__attribute__((address_space(3))) void*)l, 16, 0, 0);
#else
  *(half8*)(l + lane * 8) = *(const half8*)(g + (size_t)lane * 8);
#endif
}

// ------------------------------------------------------------- aug writer ----
// qaug/kaug: 16-dim fp16 aug vectors (geo term via one MFMA, dims 12-15 zero).
// xzT3 layout: A-operand tiles for 16x16x16 MFMA.
// xzT3[kt2][f(4)][quad(4)][m(16)][j(4)]: comp[m] of key kt2*64+f*16+quad*4+j,
// comp = {1, xh, yh, zh, xl, yl, zl, 0...}.
__device__ inline void write_aug(int q, float x, float y, float z,
                                 h16* __restrict__ qaug, h16* __restrict__ kaug,
                                 h16* __restrict__ xzT3) {
  float sx = 0.5f * LN2INV * x, sy = 0.5f * LN2INV * y, sz = 0.5f * LN2INV * z;
  h16 shx = (h16)sx, shy = (h16)sy, shz = (h16)sz;
  h16 slx = (h16)(sx - (float)shx), sly = (h16)(sy - (float)shy), slz = (h16)(sz - (float)shz);
  h16 hx = (h16)x, hy = (h16)y, hz = (h16)z;
  h16 lx = (h16)(x - (float)hx), ly = (h16)(y - (float)hy), lz = (h16)(z - (float)hz);
  float n2n = -0.25f * LN2INV * (x * x + y * y + z * z);
  h16 nh = (h16)n2n, nl = (h16)(n2n - (float)nh);
  h16 qa[16], ka[16];
  #pragma unroll
  for (int i = 0; i < 16; ++i) { qa[i] = (h16)0.f; ka[i] = (h16)0.f; }
  qa[0] = shx; qa[1] = shy; qa[2] = shz;       // pairs A d0-2 = hk
  qa[3] = shx; qa[4] = shy; qa[5] = shz;       // pairs A d3-5 = lk
  qa[6] = slx; qa[7] = sly; qa[8] = slz;       // pairs A d6-8 = hk
  qa[9] = (h16)1.f; qa[10] = (h16)1.f;         // pairs key-norm hi/lo
  qa[11] = (h16)n2n;                           // query norm (row-const)
  ka[0] = hx; ka[1] = hy; ka[2] = hz;
  ka[3] = lx; ka[4] = ly; ka[5] = lz;
  ka[6] = hx; ka[7] = hy; ka[8] = hz;
  ka[9] = nh; ka[10] = nl;
  ka[11] = (h16)1.f;
  *(half8*)(qaug + (size_t)q * 16) = ((half8*)qa)[0];
  *(half8*)(qaug + (size_t)q * 16 + 8) = ((half8*)qa)[1];
  *(half8*)(kaug + (size_t)q * 16) = ((half8*)ka)[0];
  *(half8*)(kaug + (size_t)q * 16 + 8) = ((half8*)ka)[1];
  int kt2 = q >> 6, kk = q & 63;
  int f = kk >> 4, qd = (kk >> 2) & 3, j = kk & 3;
  h16* b = xzT3 + ((size_t)kt2 << 10) + f * 256 + qd * 64 + j;
  b[0] = (h16)1.f;
  b[4] = hx; b[8] = hy; b[12] = hz;
  b[16] = lx; b[20] = ly; b[24] = lz;
  #pragma unroll
  for (int m = 7; m < 16; ++m) b[m * 4] = (h16)0.f;
}

// ------------------------------------------------- convert + initial aug -----
// Also zeroes numT (exactly NN*DD floats, same index range as xb) -- removes
// the separate hipMemsetAsync dispatch.
__global__ __launch_bounds__(256) void k_convert(
    const float* __restrict__ x, const float* __restrict__ xyz,
    h16* __restrict__ xb, h16* __restrict__ qaug,
    h16* __restrict__ kaug, h16* __restrict__ xzT3,
    float* __restrict__ numT) {
  int t = blockIdx.x * 256 + threadIdx.x;
  const int NX = NN * DD;
  if (t < NX) { xb[t] = (h16)x[t]; numT[t] = 0.f; return; }
  int q = t - NX;
  if (q < NN) write_aug(q, xyz[q * 3], xyz[q * 3 + 1], xyz[q * 3 + 2], qaug, kaug, xzT3);
}

// --------------------------------------------------------- W transpose -------
__global__ __launch_bounds__(256) void k_wt(
    const float* __restrict__ Wq, const float* __restrict__ Wk,
    const float* __restrict__ Wv, const float* __restrict__ Wo,
    h16* __restrict__ wtq, h16* __restrict__ wtk, h16* __restrict__ wtv,
    h16* __restrict__ wto) {
  __shared__ float tile[32][33];
  int m = blockIdx.z;
  const float* W = (m == 0) ? Wq : (m == 1) ? Wk : (m == 2) ? Wv : Wo;
  h16* wt = (m == 0) ? wtq : (m == 1) ? wtk : (m == 2) ? wtv : wto;
  int n0 = blockIdx.x * 32, k0 = blockIdx.y * 32;
  int tx = threadIdx.x & 31, ty = threadIdx.x >> 5;   // 32 x 8
  #pragma unroll
  for (int i = 0; i < 4; ++i)
    tile[ty + i * 8][tx] = W[(size_t)(k0 + ty + i * 8) * 256 + n0 + tx];
  __syncthreads();
  #pragma unroll
  for (int i = 0; i < 4; ++i)
    wt[(size_t)(n0 + ty + i * 8) * 256 + k0 + tx] = (h16)tile[tx][ty + i * 8];
}

// ---------------------------------------------------------------- prep dy ----
// vec4 loads (48 independent loads/thread), bitwise mask, 1024-col blocks,
// coalesced half8 stores in MFMA C-fragment layout.
__global__ __launch_bounds__(256) void k_prep(
    const float* __restrict__ dy, const int* __restrict__ dm,
    const int* __restrict__ bim, h16* __restrict__ dynT3) {
  __shared__ h16 sv[16][1036];
  int qt = blockIdx.y;                 // 0..191  (16 query rows)
  int cb = blockIdx.x;                 // 0..2    (1024 key cols)
  int t = threadIdx.x;
  int c0 = cb * 1024 + t * 4;
  #pragma unroll
  for (int r = 0; r < 16; ++r) {
    int row = qt * 16 + r;
    size_t idx = (size_t)row * NN + c0;
    int4 m4 = *(const int4*)(dm + idx);
    int4 b4 = *(const int4*)(bim + idx);
    float4 d4 = *(const float4*)(dy + idx);
    h16* s = &sv[r][t * 4];
    int mm[4] = {m4.x & b4.x, m4.y & b4.y, m4.z & b4.z, m4.w & b4.w};
    float dd[4] = {d4.x, d4.y, d4.z, d4.w};
    #pragma unroll
    for (int j = 0; j < 4; ++j) {
      bool diag = (row == c0 + j);
      bool valid = (mm[j] != 0) | diag;
      s[j] = (h16)(valid ? (-LN2INV * (dd[j] + (diag ? 2.5e-5f : 0.f))) : -43281.f);
    }
  }
  __syncthreads();
  #pragma unroll
  for (int s2 = 0; s2 < 8; ++s2) {
    int s = t + s2 * 256;              // 0..2047 : 16 tiles x 128 half8 slots
    int tile = s >> 7;
    int sl = s & 127;                  // chunk*64 + lane
    int chunk = sl >> 6;
    int lane = sl & 63;
    int row = lane & 15, quad = lane >> 4;
    int base = tile * 64 + chunk * 32 + quad * 4;
    half4 lo = *(const half4*)&sv[row][base];
    half4 hi = *(const half4*)&sv[row][base + 16];
    half8 o;
    #pragma unroll
    for (int j = 0; j < 4; ++j) { o[j] = lo[j]; o[j + 4] = hi[j]; }
    h16* dst = dynT3 + (((size_t)qt * NKT2 + (cb * 16 + tile)) << 10) + sl * 8;
    *(half8*)dst = o;
  }
}

// ------------------------------------------------------------------- gemm ----
// mode 0: fp16 row-major *scale; mode 2: fp32 +resid;
// mode 3: fp16 per-head contiguous kbh[h][token][32];
// mode 4: fp16 MFMA-A-layout vA[h*2+half][tile(192)][quad(4)][dim(16)][j(4)]
__device__ inline void gemm_body(const h16* __restrict__ A, const h16* __restrict__ Bt,
                                 const float* __restrict__ bias, void* __restrict__ out,
                                 const float* __restrict__ resid, int M, int mode,
                                 float scale, int bx, int by) {
  int lane = threadIdx.x & 63;
  int wave = threadIdx.x >> 6;
  int col = lane & 15, quad = lane >> 4;
  int m0 = bx * 32;
  int n0 = by * 64 + wave * 16;
  f32x4 acc[2];
  acc[0] = (f32x4){0.f, 0.f, 0.f, 0.f};
  acc[1] = (f32x4){0.f, 0.f, 0.f, 0.f};
  #pragma unroll
  for (int kk = 0; kk < DD; kk += 32) {
    half8 b = *(const half8*)(Bt + (size_t)(n0 + col) * DD + kk + quad * 8);
    #pragma unroll
    for (int mr = 0; mr < 2; ++mr) {
      half8 a = *(const half8*)(A + (size_t)(m0 + mr * 16 + col) * DD + kk + quad * 8);
      acc[mr] = __builtin_amdgcn_mfma_f32_16x16x32_f16(a, b, acc[mr], 0, 0, 0);
    }
  }
  float bb = bias[n0 + col];
  #pragma unroll
  for (int mr = 0; mr < 2; ++mr) {
    #pragma unroll
    for (int r = 0; r < 4; ++r) {
      int m = m0 + mr * 16 + quad * 4 + r;
      int n = n0 + col;
      float v = acc[mr][r] + bb;
      if (mode == 0)      ((h16*)out)[(size_t)m * DD + n] = (h16)(v * scale);
      else if (mode == 3) ((h16*)out)[((size_t)(n >> 5) * NN + m) * 32 + (n & 31)] = (h16)v;
      else if (mode == 4) {
        int hh = n >> 5, d = n & 31;
        size_t a = ((((size_t)hh * 2 + (d >> 4)) * (NN / 16) + (m >> 4)) * 64 +
                    ((m >> 2) & 3) * 16 + (d & 15)) * 4 + (m & 3);
        ((h16*)out)[a] = (h16)v;
      }
      else ((float*)out)[(size_t)m * DD + n] = v + resid[(size_t)m * DD + n];
    }
  }
}

__global__ __launch_bounds__(256) void k_gemm(
    const h16* __restrict__ A, const h16* __restrict__ Bt,
    const float* __restrict__ bias, void* __restrict__ out,
    const float* __restrict__ resid, int M, int mode, float scale) {
  gemm_body(A, Bt, bias, out, resid, M, mode, scale, blockIdx.x, blockIdx.y);
}

__global__ __launch_bounds__(256) void k_gemm3(
    const h16* __restrict__ A, const h16* __restrict__ wtq,
    const h16* __restrict__ wtk, const h16* __restrict__ wtv,
    const float* __restrict__ bq, const float* __restrict__ bk,
    const float* __restrict__ bv, h16* __restrict__ qb, h16* __restrict__ kbh,
    h16* __restrict__ vA, float qscale) {
  int z = blockIdx.z;
  const h16* Bt = (z == 0) ? wtq : (z == 1) ? wtk : wtv;
  const float* bias = (z == 0) ? bq : (z == 1) ? bk : bv;
  void* out = (z == 0) ? (void*)qb : (z == 1) ? (void*)kbh : (void*)vA;
  int mode = (z == 0) ? 0 : (z == 1) ? 3 : 4;
  gemm_body(A, Bt, bias, out, nullptr, NN, mode, (z == 0) ? qscale : 1.f,
            blockIdx.x, blockIdx.y);
}

// ------------------------------------------------------------- mean shift ----
// r7 core exactly (known-good 60.2 us): transpose-free PV, NO setprio (T5
// regressed +8us here -- lockstep barrier-synced waves, the m190 regime),
// xa loads inside the f-loop (hoist was part of the regressing bundle).
__device__ __forceinline__ void stage_tile(int h, int lane, int qt, int kt2,
                                           const h16* __restrict__ dynT3,
                                           const h16* __restrict__ kaug,
                                           const h16* __restrict__ xzT3,
                                           h16* bdy, h16* bka, h16* bxz) {
  if (h < 2)
    async16(dynT3 + (((size_t)qt * NKT2 + kt2) << 10) + h * 512, bdy + h * 512, lane);
  else if (h < 4)
    async16(kaug + ((size_t)kt2 << 10) + (h - 2) * 512, bka + (h - 2) * 512, lane);
  else if (h < 6)
    async16(xzT3 + ((size_t)kt2 << 10) + (h - 4) * 512, bxz + (h - 4) * 512, lane);
}

__device__ __forceinline__ void ldkf(const h16* __restrict__ kbh_h, int k0,
                                     int col, int quad, half8 kf[4]) {
  #pragma unroll
  for (int f = 0; f < 4; ++f)
    kf[f] = *(const half8*)(kbh_h + (size_t)(k0 + f * 16 + col) * 32 + quad * 8);
}

template <int LAST>
__device__ __forceinline__ void ms_compute(
    const h16* __restrict__ bdy, const h16* __restrict__ bka,
    const h16* __restrict__ bxz, const half8 kf[4], half8 qaf, half8 qf,
    const h16* __restrict__ vA0, int lane, int col, int quad,
    f32x4& accS, f32x4& fc0, f32x4& fc1) {
  half8 kz = {};
  half8 dv0 = *(const half8*)(bdy + lane * 8);
  half8 dv1 = *(const half8*)(bdy + 512 + lane * 8);
  #pragma unroll
  for (int f = 0; f < 4; ++f) {
    half8 ka = (quad < 2) ? *(const half8*)(bka + (f * 16 + col) * 16 + quad * 8) : kz;
    half8 dv = (f & 2) ? dv1 : dv0;
    f32x4 cc;
    #pragma unroll
    for (int r = 0; r < 4; ++r) cc[r] = (float)dv[(f & 1) * 4 + r];
    f32x4 g = __builtin_amdgcn_mfma_f32_16x16x32_f16(ka, qaf, cc, 0, 0, 0);
    f32x4 s = __builtin_amdgcn_mfma_f32_16x16x32_f16(kf[f], qf, g, 0, 0, 0);
    half4 pv;
    #pragma unroll
    for (int r = 0; r < 4; ++r) pv[r] = (h16)EXP2(s[r]);
    half4 xa = *(const half4*)(bxz + f * 256 + lane * 4);
    accS = MFMA16(xa, pv, accS);
    if (LAST) {
      half4 v0 = *(const half4*)(vA0 + f * 256 + lane * 4);
      half4 v1 = *(const half4*)(vA0 + VHALF + f * 256 + lane * 4);
      fc0 = MFMA16(v0, pv, fc0);
      fc1 = MFMA16(v1, pv, fc1);
    }
  }
}

template <int LAST>
__global__ __launch_bounds__(512, 4) void k_msattn(
    const h16* __restrict__ qb, const h16* __restrict__ kbh,
    const h16* __restrict__ vA, const h16* __restrict__ dynT3,
    const h16* __restrict__ qaug, const h16* __restrict__ kaug,
    const h16* __restrict__ xzT3, float* __restrict__ den_s,
    float* __restrict__ axh_s, float* __restrict__ axl_s,
    float* __restrict__ numT) {
  __shared__ h16 s_dy[2][1024];
  __shared__ h16 s_ka[2][1024];
  __shared__ h16 s_xz[2][1024];
  const int tid = threadIdx.x;
  const int h = tid >> 6;
  const int lane = tid & 63;
  const int col = lane & 15;
  const int quad = lane >> 4;
  const int qt = blockIdx.x;
  const int q0 = qt * 16;
  const int tb = blockIdx.y * KT;

  half8 kz = {};
  half8 qf = *(const half8*)(qb + (size_t)(q0 + col) * DD + h * 32 + quad * 8);
  half8 qaf = (quad < 2) ? *(const half8*)(qaug + (size_t)(q0 + col) * 16 + quad * 8) : kz;
  const h16* kbh_h = kbh + (size_t)h * NN * 32;
  const h16* vb = vA + (size_t)h * 2 * (NN / 16) * 256;   // head base
  f32x4 accS = (f32x4){0.f, 0.f, 0.f, 0.f};
  f32x4 fc0 = (f32x4){0.f, 0.f, 0.f, 0.f};
  f32x4 fc1 = (f32x4){0.f, 0.f, 0.f, 0.f};
  half8 kfA[4], kfB[4];

  stage_tile(h, lane, qt, tb, dynT3, kaug, xzT3, s_dy[0], s_ka[0], s_xz[0]);
  ldkf(kbh_h, tb * 64, col, quad, kfA);
  __syncthreads();          // drains async stage + kfA
  #pragma unroll 1
  for (int kt = 0; kt < KT; kt += 2) {
    int t1 = tb + kt + 1;
    stage_tile(h, lane, qt, t1, dynT3, kaug, xzT3, s_dy[1], s_ka[1], s_xz[1]);
    ldkf(kbh_h, t1 * 64, col, quad, kfB);
    ms_compute<LAST>(s_dy[0], s_ka[0], s_xz[0], kfA, qaf, qf,
                     vb + (size_t)(tb + kt) * 1024,
                     lane, col, quad, accS, fc0, fc1);
    __syncthreads();        // buf1 + kfB now resident
    int t2 = (kt + 2 < KT) ? tb + kt + 2 : t1;
    if (kt + 2 < KT)
      stage_tile(h, lane, qt, t2, dynT3, kaug, xzT3, s_dy[0], s_ka[0], s_xz[0]);
    ldkf(kbh_h, t2 * 64, col, quad, kfA);
    ms_compute<LAST>(s_dy[1], s_ka[1], s_xz[1], kfB, qaf, qf,
                     vb + (size_t)t1 * 1024,
                     lane, col, quad, accS, fc0, fc1);
    __syncthreads();
  }

  // accS D rows: 0=den, 1-3=num_hi, 4-6=num_lo
  int q = q0 + col;
  size_t sidx = (size_t)(blockIdx.y * NH + h) * NN + q;
  if (quad == 0) {
    den_s[sidx] = accS[0];
    axh_s[sidx * 3 + 0] = accS[1];
    axh_s[sidx * 3 + 1] = accS[2];
    axh_s[sidx * 3 + 2] = accS[3];
  } else if (quad == 1) {
    axl_s[sidx * 3 + 0] = accS[0];
    axl_s[sidx * 3 + 1] = accS[1];
    axl_s[sidx * 3 + 2] = accS[2];
  }
  if (LAST) {
    #pragma unroll
    for (int r = 0; r < 4; ++r) {
      atomicAdd(&numT[(size_t)(h * 32 + quad * 4 + r) * NN + q], fc0[r]);
      atomicAdd(&numT[(size_t)(h * 32 + 16 + quad * 4 + r) * NN + q], fc1[r]);
    }
  }
}

// ---------------------------------------------------------------- combine ----
// Parallel version: 96 blocks x (32 q x 8 h) threads; per-thread 4-split sum,
// then width-8 shfl_xor reduction over heads.
__global__ __launch_bounds__(256) void k_combine(
    const float* __restrict__ den_s, const float* __restrict__ axh_s,
    const float* __restrict__ axl_s, float* __restrict__ den_tot,
    h16* __restrict__ qaug, h16* __restrict__ kaug, h16* __restrict__ xzT3,
    float* __restrict__ out3) {
  int h = threadIdx.x & 7;
  int q = blockIdx.x * 32 + (threadIdx.x >> 3);
  float d = 0.f, x = 0.f, y = 0.f, z = 0.f;
  #pragma unroll
  for (int s = 0; s < SPLIT; ++s) {
    size_t idx = (size_t)(s * NH + h) * NN + q;
    d += den_s[idx];
    x += axh_s[idx * 3 + 0] + axl_s[idx * 3 + 0];
    y += axh_s[idx * 3 + 1] + axl_s[idx * 3 + 1];
    z += axh_s[idx * 3 + 2] + axl_s[idx * 3 + 2];
  }
  den_tot[h * NN + q] = d;
  float inv = 0.125f / d;
  float X = x * inv, Y = y * inv, Z = z * inv;
  #pragma unroll
  for (int m = 1; m < 8; m <<= 1) {
    X += __shfl_xor(X, m);
    Y += __shfl_xor(Y, m);
    Z += __shfl_xor(Z, m);
  }
  if (h == 0) {
    if (out3) {
      out3[q * 3 + 0] = X;
      out3[q * 3 + 1] = Y;
      out3[q * 3 + 2] = Z;
    } else {
      write_aug(q, X, Y, Z, qaug, kaug, xzT3);
    }
  }
}

// ----------------------------------------------------------------- finish ----
__global__ __launch_bounds__(256) void k_finish(
    const float* __restrict__ numT, const float* __restrict__ den_tot,
    h16* __restrict__ featb) {
  __shared__ float tile[32][33];
  int q0 = blockIdx.x * 32, d0 = blockIdx.y * 32;
  int tx = threadIdx.x & 31, ty = threadIdx.x >> 5;   // 32 x 8
  #pragma unroll
  for (int i = 0; i < 4; ++i)
    tile[ty + i * 8][tx] = numT[(size_t)(d0 + ty + i * 8) * NN + q0 + tx];
  __syncthreads();
  int h = d0 >> 5;
  #pragma unroll
  for (int i = 0; i < 4; ++i) {
    int q = q0 + ty + i * 8;
    float inv = 1.f / den_tot[h * NN + q];
    featb[(size_t)q * DD + d0 + tx] = (h16)(tile[tx][ty + i * 8] * inv);
  }
}

// ----------------------------------------------------------------- launch ----
extern "C" void kernel_launch(void* const* d_in, const int* in_sizes, int n_in,
                              void* d_out, int out_size, void* d_ws, size_t ws_size,
                              hipStream_t stream) {
  const float* x   = (const float*)d_in[0];
  const float* xyz = (const float*)d_in[1];
  const float* dy  = (const float*)d_in[2];
  const int* dm    = (const int*)d_in[3];
  const int* bim   = (const int*)d_in[4];
  const float* Wq = (const float*)d_in[5];
  const float* bq = (const float*)d_in[6];
  const float* Wk = (const float*)d_in[7];
  const float* bk = (const float*)d_in[8];
  const float* Wv = (const float*)d_in[9];
  const float* bv = (const float*)d_in[10];
  const float* Wo = (const float*)d_in[11];
  const float* bo = (const float*)d_in[12];

  char* p = (char*)d_ws;
  h16* xb  = (h16*)p; p += (size_t)NN * DD * 2;
  h16* wtq = (h16*)p; p += 256 * 256 * 2;
  h16* wtk = (h16*)p; p += 256 * 256 * 2;
  h16* wtv = (h16*)p; p += 256 * 256 * 2;
  h16* wto = (h16*)p; p += 256 * 256 * 2;
  h16* qb    = (h16*)p; p += (size_t)NN * DD * 2;
  h16* kbh   = (h16*)p; p += (size_t)NN * DD * 2;
  h16* vA    = (h16*)p; p += (size_t)NN * DD * 2;
  h16* featb = (h16*)p; p += (size_t)NN * DD * 2;
  h16* dynT3 = (h16*)p; p += (size_t)NN * NN * 2;
  h16* qaug  = (h16*)p; p += (size_t)NN * 16 * 2;
  h16* kaug  = (h16*)p; p += (size_t)NN * 16 * 2;
  h16* xzT3  = (h16*)p; p += (size_t)NKT2 * 1024 * 2;
  float* den_s = (float*)p; p += (size_t)SPLIT * NH * NN * 4;
  float* axh_s = (float*)p; p += (size_t)SPLIT * NH * NN * 3 * 4;
  float* axl_s = (float*)p; p += (size_t)SPLIT * NH * NN * 3 * 4;
  float* den_tot = (float*)p; p += (size_t)NH * NN * 4;
  float* numT = (float*)p; p += (size_t)DD * NN * 4;

  k_convert<<<(NN * DD + NN + 255) / 256, 256, 0, stream>>>(x, xyz, xb, qaug,
                                                            kaug, xzT3, numT);
  k_wt<<<dim3(8, 8, 4), 256, 0, stream>>>(Wq, Wk, Wv, Wo, wtq, wtk, wtv, wto);
  k_prep<<<dim3(3, 192), 256, 0, stream>>>(dy, dm, bim, dynT3);
  k_gemm3<<<dim3(96, 4, 3), 256, 0, stream>>>(xb, wtq, wtk, wtv, bq, bk, bv,
                                              qb, kbh, vA,
                                              0.17677669529663689f * LN2INV);

  float* xyz_final = (float*)d_out;            // output 0: [3072,3]
  float* out_final = (float*)d_out + NN * 3;   // output 1: [3072,256]

  k_msattn<0><<<dim3(NN / 16, SPLIT), 512, 0, stream>>>(
      qb, kbh, vA, dynT3, qaug, kaug, xzT3, den_s, axh_s, axl_s, nullptr);
  k_combine<<<96, 256, 0, stream>>>(den_s, axh_s, axl_s, den_tot,
                                    qaug, kaug, xzT3, nullptr);
  k_msattn<0><<<dim3(NN / 16, SPLIT), 512, 0, stream>>>(
      qb, kbh, vA, dynT3, qaug, kaug, xzT3, den_s, axh_s, axl_s, nullptr);
  k_combine<<<96, 256, 0, stream>>>(den_s, axh_s, axl_s, den_tot,
                                    qaug, kaug, xzT3, nullptr);
  k_msattn<1><<<dim3(NN / 16, SPLIT), 512, 0, stream>>>(
      qb, kbh, vA, dynT3, qaug, kaug, xzT3, den_s, axh_s, axl_s, numT);
  k_combine<<<96, 256, 0, stream>>>(den_s, axh_s, axl_s, den_tot,
                                    nullptr, nullptr, nullptr, xyz_final);
  k_finish<<<dim3(96, 8), 256, 0, stream>>>(numT, den_tot, featb);
  k_gemm<<<dim3(96, 4), 256, 0, stream>>>(featb, wto, bo, out_final, x, NN, 2, 1.f);
}

// Round 10
// 312.355 us; speedup vs baseline: 1.2662x; 1.0255x over previous
//
#include <hip/hip_runtime.h>
#include <hip/hip_fp16.h>

#define NN 3072
#define DD 256
#define NH 8
#define SPLIT 4
#define KT (NN / SPLIT / 64)   // 12 key-tiles of 64 per split
#define NKT2 (NN / 64)         // 48 global key tiles
#define VHALF ((NN / 16) * 256)   // 49152: stride between v-dim halves
#define LN2INV 1.4426950408889634f
#define PREP_BLKS 576                      // 3 x 192
#define CONV_BLKS ((NN * DD + NN) / 256)   // 3084
#define WT_BLKS 256                        // 8 x 8 x 4

typedef _Float16 h16;
typedef __attribute__((ext_vector_type(4))) _Float16 half4;
typedef __attribute__((ext_vector_type(8))) _Float16 half8;
typedef __attribute__((ext_vector_type(4))) float f32x4;

#if __has_builtin(__builtin_amdgcn_exp2f)
#define EXP2(x) __builtin_amdgcn_exp2f(x)
#else
#define EXP2(x) __expf((x) * 0.69314718056f)
#endif

// K=16 f16 MFMA (legacy naming: no underscore before f16 -- gfx950 keeps it).
// B-fragment layout (k=quad*4+j, n=lane&15) EXACTLY matches the C-fragment of
// the score MFMA -> P feeds PV/sum MFMAs straight from registers.
#define MFMA16(a, b, c) __builtin_amdgcn_mfma_f32_16x16x16f16(a, b, c, 0, 0, 0)

// --------------------------------------------------------- async 16B stage ---
__device__ __forceinline__ void async16(const h16* g, h16* l, int lane) {
#if __has_builtin(__builtin_amdgcn_global_load_lds)
  __builtin_amdgcn_global_load_lds(
      (const __attribute__((address_space(1))) void*)(g + (size_t)lane * 8),
      (__attribute__((address_space(3))) void*)l, 16, 0, 0);
#else
  *(half8*)(l + lane * 8) = *(const half8*)(g + (size_t)lane * 8);
#endif
}

// ------------------------------------------------------------- aug writer ----
// qaug/kaug: 16-dim fp16 aug vectors (geo term via one MFMA, dims 12-15 zero).
// xzT3 layout: A-operand tiles for 16x16x16 MFMA.
// xzT3[kt2][f(4)][quad(4)][m(16)][j(4)]: comp[m] of key kt2*64+f*16+quad*4+j,
// comp = {1, xh, yh, zh, xl, yl, zl, 0...}.
__device__ inline void write_aug(int q, float x, float y, float z,
                                 h16* __restrict__ qaug, h16* __restrict__ kaug,
                                 h16* __restrict__ xzT3) {
  float sx = 0.5f * LN2INV * x, sy = 0.5f * LN2INV * y, sz = 0.5f * LN2INV * z;
  h16 shx = (h16)sx, shy = (h16)sy, shz = (h16)sz;
  h16 slx = (h16)(sx - (float)shx), sly = (h16)(sy - (float)shy), slz = (h16)(sz - (float)shz);
  h16 hx = (h16)x, hy = (h16)y, hz = (h16)z;
  h16 lx = (h16)(x - (float)hx), ly = (h16)(y - (float)hy), lz = (h16)(z - (float)hz);
  float n2n = -0.25f * LN2INV * (x * x + y * y + z * z);
  h16 nh = (h16)n2n, nl = (h16)(n2n - (float)nh);
  h16 qa[16], ka[16];
  #pragma unroll
  for (int i = 0; i < 16; ++i) { qa[i] = (h16)0.f; ka[i] = (h16)0.f; }
  qa[0] = shx; qa[1] = shy; qa[2] = shz;       // pairs A d0-2 = hk
  qa[3] = shx; qa[4] = shy; qa[5] = shz;       // pairs A d3-5 = lk
  qa[6] = slx; qa[7] = sly; qa[8] = slz;       // pairs A d6-8 = hk
  qa[9] = (h16)1.f; qa[10] = (h16)1.f;         // pairs key-norm hi/lo
  qa[11] = (h16)n2n;                           // query norm (row-const)
  ka[0] = hx; ka[1] = hy; ka[2] = hz;
  ka[3] = lx; ka[4] = ly; ka[5] = lz;
  ka[6] = hx; ka[7] = hy; ka[8] = hz;
  ka[9] = nh; ka[10] = nl;
  ka[11] = (h16)1.f;
  *(half8*)(qaug + (size_t)q * 16) = ((half8*)qa)[0];
  *(half8*)(qaug + (size_t)q * 16 + 8) = ((half8*)qa)[1];
  *(half8*)(kaug + (size_t)q * 16) = ((half8*)ka)[0];
  *(half8*)(kaug + (size_t)q * 16 + 8) = ((half8*)ka)[1];
  int kt2 = q >> 6, kk = q & 63;
  int f = kk >> 4, qd = (kk >> 2) & 3, j = kk & 3;
  h16* b = xzT3 + ((size_t)kt2 << 10) + f * 256 + qd * 64 + j;
  b[0] = (h16)1.f;
  b[4] = hx; b[8] = hy; b[12] = hz;
  b[16] = lx; b[20] = ly; b[24] = lz;
  #pragma unroll
  for (int m = 7; m < 16; ++m) b[m * 4] = (h16)0.f;
}

// --------------------------------------------------- fused prologue ----------
// One dispatch covering: [0,576) prep-dy, [576,576+3084) convert+aug+numT-zero,
// [3660,3916) W-transpose. The three are independent; fusing overlaps the
// memory-bound prep stream with the scattered convert/wt work and removes two
// dispatch gaps.
__global__ __launch_bounds__(256) void k_pre(
    const float* __restrict__ x, const float* __restrict__ xyz,
    const float* __restrict__ dy, const int* __restrict__ dm,
    const int* __restrict__ bim,
    const float* __restrict__ Wq, const float* __restrict__ Wk,
    const float* __restrict__ Wv, const float* __restrict__ Wo,
    h16* __restrict__ xb, h16* __restrict__ qaug, h16* __restrict__ kaug,
    h16* __restrict__ xzT3, float* __restrict__ numT,
    h16* __restrict__ wtq, h16* __restrict__ wtk, h16* __restrict__ wtv,
    h16* __restrict__ wto, h16* __restrict__ dynT3) {
  __shared__ h16 sv[16][1036];          // 33 KB; wt branch reuses as fp32 tile
  int b = blockIdx.x;
  int t = threadIdx.x;
  if (b < PREP_BLKS) {
    // ---- prep: vec4 loads, bitwise mask, coalesced half8 fragment stores ----
    int cb = b % 3, qt = b / 3;
    int c0 = cb * 1024 + t * 4;
    #pragma unroll
    for (int r = 0; r < 16; ++r) {
      int row = qt * 16 + r;
      size_t idx = (size_t)row * NN + c0;
      int4 m4 = *(const int4*)(dm + idx);
      int4 b4 = *(const int4*)(bim + idx);
      float4 d4 = *(const float4*)(dy + idx);
      h16* s = &sv[r][t * 4];
      int mm[4] = {m4.x & b4.x, m4.y & b4.y, m4.z & b4.z, m4.w & b4.w};
      float dd[4] = {d4.x, d4.y, d4.z, d4.w};
      #pragma unroll
      for (int j = 0; j < 4; ++j) {
        bool diag = (row == c0 + j);
        bool valid = (mm[j] != 0) | diag;
        s[j] = (h16)(valid ? (-LN2INV * (dd[j] + (diag ? 2.5e-5f : 0.f))) : -43281.f);
      }
    }
    __syncthreads();
    #pragma unroll
    for (int s2 = 0; s2 < 8; ++s2) {
      int s = t + s2 * 256;              // 0..2047 : 16 tiles x 128 half8 slots
      int tile = s >> 7;
      int sl = s & 127;                  // chunk*64 + lane
      int lane = sl & 63;
      int row = lane & 15, quad = lane >> 4;
      int base = tile * 64 + (sl >> 6) * 32 + quad * 4;
      half4 lo = *(const half4*)&sv[row][base];
      half4 hi = *(const half4*)&sv[row][base + 16];
      half8 o;
      #pragma unroll
      for (int j = 0; j < 4; ++j) { o[j] = lo[j]; o[j + 4] = hi[j]; }
      h16* dst = dynT3 + (((size_t)qt * NKT2 + (cb * 16 + tile)) << 10) + sl * 8;
      *(half8*)dst = o;
    }
  } else if (b < PREP_BLKS + CONV_BLKS) {
    // ---- convert + initial aug + numT zero ----
    int u = (b - PREP_BLKS) * 256 + t;
    const int NX = NN * DD;
    if (u < NX) { xb[u] = (h16)x[u]; numT[u] = 0.f; return; }
    int q = u - NX;
    if (q < NN)
      write_aug(q, xyz[q * 3], xyz[q * 3 + 1], xyz[q * 3 + 2], qaug, kaug, xzT3);
  } else {
    // ---- W transpose via 32x32 LDS tile (reuses sv storage as fp32) ----
    float* tf = (float*)sv;              // [32][33]
    int w = b - PREP_BLKS - CONV_BLKS;
    int m = w >> 6;
    int n0 = (w & 7) * 32, k0 = ((w >> 3) & 7) * 32;
    const float* W = (m == 0) ? Wq : (m == 1) ? Wk : (m == 2) ? Wv : Wo;
    h16* wt = (m == 0) ? wtq : (m == 1) ? wtk : (m == 2) ? wtv : wto;
    int tx = t & 31, ty = t >> 5;        // 32 x 8
    #pragma unroll
    for (int i = 0; i < 4; ++i)
      tf[(ty + i * 8) * 33 + tx] = W[(size_t)(k0 + ty + i * 8) * 256 + n0 + tx];
    __syncthreads();
    #pragma unroll
    for (int i = 0; i < 4; ++i)
      wt[(size_t)(n0 + ty + i * 8) * 256 + k0 + tx] = (h16)tf[tx * 33 + ty + i * 8];
  }
}

// ------------------------------------------------------------------- gemm ----
// mode 0: fp16 row-major *scale; mode 2: fp32 +resid;
// mode 3: fp16 per-head contiguous kbh[h][token][32];
// mode 4: fp16 MFMA-A-layout vA[h*2+half][tile(192)][quad(4)][dim(16)][j(4)]
__device__ inline void gemm_body(const h16* __restrict__ A, const h16* __restrict__ Bt,
                                 const float* __restrict__ bias, void* __restrict__ out,
                                 const float* __restrict__ resid, int M, int mode,
                                 float scale, int bx, int by) {
  int lane = threadIdx.x & 63;
  int wave = threadIdx.x >> 6;
  int col = lane & 15, quad = lane >> 4;
  int m0 = bx * 32;
  int n0 = by * 64 + wave * 16;
  f32x4 acc[2];
  acc[0] = (f32x4){0.f, 0.f, 0.f, 0.f};
  acc[1] = (f32x4){0.f, 0.f, 0.f, 0.f};
  #pragma unroll
  for (int kk = 0; kk < DD; kk += 32) {
    half8 b = *(const half8*)(Bt + (size_t)(n0 + col) * DD + kk + quad * 8);
    #pragma unroll
    for (int mr = 0; mr < 2; ++mr) {
      half8 a = *(const half8*)(A + (size_t)(m0 + mr * 16 + col) * DD + kk + quad * 8);
      acc[mr] = __builtin_amdgcn_mfma_f32_16x16x32_f16(a, b, acc[mr], 0, 0, 0);
    }
  }
  float bb = bias[n0 + col];
  #pragma unroll
  for (int mr = 0; mr < 2; ++mr) {
    #pragma unroll
    for (int r = 0; r < 4; ++r) {
      int m = m0 + mr * 16 + quad * 4 + r;
      int n = n0 + col;
      float v = acc[mr][r] + bb;
      if (mode == 0)      ((h16*)out)[(size_t)m * DD + n] = (h16)(v * scale);
      else if (mode == 3) ((h16*)out)[((size_t)(n >> 5) * NN + m) * 32 + (n & 31)] = (h16)v;
      else if (mode == 4) {
        int hh = n >> 5, d = n & 31;
        size_t a = ((((size_t)hh * 2 + (d >> 4)) * (NN / 16) + (m >> 4)) * 64 +
                    ((m >> 2) & 3) * 16 + (d & 15)) * 4 + (m & 3);
        ((h16*)out)[a] = (h16)v;
      }
      else ((float*)out)[(size_t)m * DD + n] = v + resid[(size_t)m * DD + n];
    }
  }
}

__global__ __launch_bounds__(256) void k_gemm(
    const h16* __restrict__ A, const h16* __restrict__ Bt,
    const float* __restrict__ bias, void* __restrict__ out,
    const float* __restrict__ resid, int M, int mode, float scale) {
  gemm_body(A, Bt, bias, out, resid, M, mode, scale, blockIdx.x, blockIdx.y);
}

__global__ __launch_bounds__(256) void k_gemm3(
    const h16* __restrict__ A, const h16* __restrict__ wtq,
    const h16* __restrict__ wtk, const h16* __restrict__ wtv,
    const float* __restrict__ bq, const float* __restrict__ bk,
    const float* __restrict__ bv, h16* __restrict__ qb, h16* __restrict__ kbh,
    h16* __restrict__ vA, float qscale) {
  int z = blockIdx.z;
  const h16* Bt = (z == 0) ? wtq : (z == 1) ? wtk : wtv;
  const float* bias = (z == 0) ? bq : (z == 1) ? bk : bv;
  void* out = (z == 0) ? (void*)qb : (z == 1) ? (void*)kbh : (void*)vA;
  int mode = (z == 0) ? 0 : (z == 1) ? 3 : 4;
  gemm_body(A, Bt, bias, out, nullptr, NN, mode, (z == 0) ? qscale : 1.f,
            blockIdx.x, blockIdx.y);
}

// ------------------------------------------------------------- mean shift ----
// r9 core (transpose-free PV, no setprio) + entry de-phasing: the 3 blocks
// co-resident on a CU ({b, b+256, b+512} under XCD round-robin) start
// simultaneously and phase-lock, so their barrier-drain windows coincide and
// the whole CU idles. Stagger starts by ~2048cy per generation so one block's
// stall overlaps another's compute.
__device__ __forceinline__ void stage_tile(int h, int lane, int qt, int kt2,
                                           const h16* __restrict__ dynT3,
                                           const h16* __restrict__ kaug,
                                           const h16* __restrict__ xzT3,
                                           h16* bdy, h16* bka, h16* bxz) {
  if (h < 2)
    async16(dynT3 + (((size_t)qt * NKT2 + kt2) << 10) + h * 512, bdy + h * 512, lane);
  else if (h < 4)
    async16(kaug + ((size_t)kt2 << 10) + (h - 2) * 512, bka + (h - 2) * 512, lane);
  else if (h < 6)
    async16(xzT3 + ((size_t)kt2 << 10) + (h - 4) * 512, bxz + (h - 4) * 512, lane);
}

__device__ __forceinline__ void ldkf(const h16* __restrict__ kbh_h, int k0,
                                     int col, int quad, half8 kf[4]) {
  #pragma unroll
  for (int f = 0; f < 4; ++f)
    kf[f] = *(const half8*)(kbh_h + (size_t)(k0 + f * 16 + col) * 32 + quad * 8);
}

template <int LAST>
__device__ __forceinline__ void ms_compute(
    const h16* __restrict__ bdy, const h16* __restrict__ bka,
    const h16* __restrict__ bxz, const half8 kf[4], half8 qaf, half8 qf,
    const h16* __restrict__ vA0, int lane, int col, int quad,
    f32x4& accS, f32x4& fc0, f32x4& fc1) {
  half8 kz = {};
  half8 dv0 = *(const half8*)(bdy + lane * 8);
  half8 dv1 = *(const half8*)(bdy + 512 + lane * 8);
  #pragma unroll
  for (int f = 0; f < 4; ++f) {
    half8 ka = (quad < 2) ? *(const half8*)(bka + (f * 16 + col) * 16 + quad * 8) : kz;
    half8 dv = (f & 2) ? dv1 : dv0;
    f32x4 cc;
    #pragma unroll
    for (int r = 0; r < 4; ++r) cc[r] = (float)dv[(f & 1) * 4 + r];
    f32x4 g = __builtin_amdgcn_mfma_f32_16x16x32_f16(ka, qaf, cc, 0, 0, 0);
    f32x4 s = __builtin_amdgcn_mfma_f32_16x16x32_f16(kf[f], qf, g, 0, 0, 0);
    half4 pv;
    #pragma unroll
    for (int r = 0; r < 4; ++r) pv[r] = (h16)EXP2(s[r]);
    half4 xa = *(const half4*)(bxz + f * 256 + lane * 4);
    accS = MFMA16(xa, pv, accS);
    if (LAST) {
      half4 v0 = *(const half4*)(vA0 + f * 256 + lane * 4);
      half4 v1 = *(const half4*)(vA0 + VHALF + f * 256 + lane * 4);
      fc0 = MFMA16(v0, pv, fc0);
      fc1 = MFMA16(v1, pv, fc1);
    }
  }
}

template <int LAST>
__global__ __launch_bounds__(512, 4) void k_msattn(
    const h16* __restrict__ qb, const h16* __restrict__ kbh,
    const h16* __restrict__ vA, const h16* __restrict__ dynT3,
    const h16* __restrict__ qaug, const h16* __restrict__ kaug,
    const h16* __restrict__ xzT3, float* __restrict__ den_s,
    float* __restrict__ axh_s, float* __restrict__ axl_s,
    float* __restrict__ numT) {
  __shared__ h16 s_dy[2][1024];
  __shared__ h16 s_ka[2][1024];
  __shared__ h16 s_xz[2][1024];
  const int tid = threadIdx.x;
  const int h = tid >> 6;
  const int lane = tid & 63;
  const int col = lane & 15;
  const int quad = lane >> 4;
  const int qt = blockIdx.x;
  const int q0 = qt * 16;
  const int tb = blockIdx.y * KT;

  // de-phase co-resident block generations (~2048cy per step)
  int phase = (blockIdx.x + gridDim.x * blockIdx.y) >> 8;   // 0,1,2
  for (int i = 0; i < phase; ++i) {
    __builtin_amdgcn_s_sleep(16);
    __builtin_amdgcn_s_sleep(16);
  }

  half8 kz = {};
  half8 qf = *(const half8*)(qb + (size_t)(q0 + col) * DD + h * 32 + quad * 8);
  half8 qaf = (quad < 2) ? *(const half8*)(qaug + (size_t)(q0 + col) * 16 + quad * 8) : kz;
  const h16* kbh_h = kbh + (size_t)h * NN * 32;
  const h16* vb = vA + (size_t)h * 2 * (NN / 16) * 256;   // head base
  f32x4 accS = (f32x4){0.f, 0.f, 0.f, 0.f};
  f32x4 fc0 = (f32x4){0.f, 0.f, 0.f, 0.f};
  f32x4 fc1 = (f32x4){0.f, 0.f, 0.f, 0.f};
  half8 kfA[4], kfB[4];

  stage_tile(h, lane, qt, tb, dynT3, kaug, xzT3, s_dy[0], s_ka[0], s_xz[0]);
  ldkf(kbh_h, tb * 64, col, quad, kfA);
  __syncthreads();          // drains async stage + kfA
  #pragma unroll 1
  for (int kt = 0; kt < KT; kt += 2) {
    int t1 = tb + kt + 1;
    stage_tile(h, lane, qt, t1, dynT3, kaug, xzT3, s_dy[1], s_ka[1], s_xz[1]);
    ldkf(kbh_h, t1 * 64, col, quad, kfB);
    ms_compute<LAST>(s_dy[0], s_ka[0], s_xz[0], kfA, qaf, qf,
                     vb + (size_t)(tb + kt) * 1024,
                     lane, col, quad, accS, fc0, fc1);
    __syncthreads();        // buf1 + kfB now resident
    int t2 = (kt + 2 < KT) ? tb + kt + 2 : t1;
    if (kt + 2 < KT)
      stage_tile(h, lane, qt, t2, dynT3, kaug, xzT3, s_dy[0], s_ka[0], s_xz[0]);
    ldkf(kbh_h, t2 * 64, col, quad, kfA);
    ms_compute<LAST>(s_dy[1], s_ka[1], s_xz[1], kfB, qaf, qf,
                     vb + (size_t)t1 * 1024,
                     lane, col, quad, accS, fc0, fc1);
    __syncthreads();
  }

  // accS D rows: 0=den, 1-3=num_hi, 4-6=num_lo
  int q = q0 + col;
  size_t sidx = (size_t)(blockIdx.y * NH + h) * NN + q;
  if (quad == 0) {
    den_s[sidx] = accS[0];
    axh_s[sidx * 3 + 0] = accS[1];
    axh_s[sidx * 3 + 1] = accS[2];
    axh_s[sidx * 3 + 2] = accS[3];
  } else if (quad == 1) {
    axl_s[sidx * 3 + 0] = accS[0];
    axl_s[sidx * 3 + 1] = accS[1];
    axl_s[sidx * 3 + 2] = accS[2];
  }
  if (LAST) {
    #pragma unroll
    for (int r = 0; r < 4; ++r) {
      atomicAdd(&numT[(size_t)(h * 32 + quad * 4 + r) * NN + q], fc0[r]);
      atomicAdd(&numT[(size_t)(h * 32 + 16 + quad * 4 + r) * NN + q], fc1[r]);
    }
  }
}

// ---------------------------------------------------------------- combine ----
// Parallel version: 96 blocks x (32 q x 8 h) threads; per-thread 4-split sum,
// then width-8 shfl_xor reduction over heads.
__global__ __launch_bounds__(256) void k_combine(
    const float* __restrict__ den_s, const float* __restrict__ axh_s,
    const float* __restrict__ axl_s, float* __restrict__ den_tot,
    h16* __restrict__ qaug, h16* __restrict__ kaug, h16* __restrict__ xzT3,
    float* __restrict__ out3) {
  int h = threadIdx.x & 7;
  int q = blockIdx.x * 32 + (threadIdx.x >> 3);
  float d = 0.f, x = 0.f, y = 0.f, z = 0.f;
  #pragma unroll
  for (int s = 0; s < SPLIT; ++s) {
    size_t idx = (size_t)(s * NH + h) * NN + q;
    d += den_s[idx];
    x += axh_s[idx * 3 + 0] + axl_s[idx * 3 + 0];
    y += axh_s[idx * 3 + 1] + axl_s[idx * 3 + 1];
    z += axh_s[idx * 3 + 2] + axl_s[idx * 3 + 2];
  }
  den_tot[h * NN + q] = d;
  float inv = 0.125f / d;
  float X = x * inv, Y = y * inv, Z = z * inv;
  #pragma unroll
  for (int m = 1; m < 8; m <<= 1) {
    X += __shfl_xor(X, m);
    Y += __shfl_xor(Y, m);
    Z += __shfl_xor(Z, m);
  }
  if (h == 0) {
    if (out3) {
      out3[q * 3 + 0] = X;
      out3[q * 3 + 1] = Y;
      out3[q * 3 + 2] = Z;
    } else {
      write_aug(q, X, Y, Z, qaug, kaug, xzT3);
    }
  }
}

// ----------------------------------------------------------------- finish ----
__global__ __launch_bounds__(256) void k_finish(
    const float* __restrict__ numT, const float* __restrict__ den_tot,
    h16* __restrict__ featb) {
  __shared__ float tile[32][33];
  int q0 = blockIdx.x * 32, d0 = blockIdx.y * 32;
  int tx = threadIdx.x & 31, ty = threadIdx.x >> 5;   // 32 x 8
  #pragma unroll
  for (int i = 0; i < 4; ++i)
    tile[ty + i * 8][tx] = numT[(size_t)(d0 + ty + i * 8) * NN + q0 + tx];
  __syncthreads();
  int h = d0 >> 5;
  #pragma unroll
  for (int i = 0; i < 4; ++i) {
    int q = q0 + ty + i * 8;
    float inv = 1.f / den_tot[h * NN + q];
    featb[(size_t)q * DD + d0 + tx] = (h16)(tile[tx][ty + i * 8] * inv);
  }
}

// ----------------------------------------------------------------- launch ----
extern "C" void kernel_launch(void* const* d_in, const int* in_sizes, int n_in,
                              void* d_out, int out_size, void* d_ws, size_t ws_size,
                              hipStream_t stream) {
  const float* x   = (const float*)d_in[0];
  const float* xyz = (const float*)d_in[1];
  const float* dy  = (const float*)d_in[2];
  const int* dm    = (const int*)d_in[3];
  const int* bim   = (const int*)d_in[4];
  const float* Wq = (const float*)d_in[5];
  const float* bq = (const float*)d_in[6];
  const float* Wk = (const float*)d_in[7];
  const float* bk = (const float*)d_in[8];
  const float* Wv = (const float*)d_in[9];
  const float* bv = (const float*)d_in[10];
  const float* Wo = (const float*)d_in[11];
  const float* bo = (const float*)d_in[12];

  char* p = (char*)d_ws;
  h16* xb  = (h16*)p; p += (size_t)NN * DD * 2;
  h16* wtq = (h16*)p; p += 256 * 256 * 2;
  h16* wtk = (h16*)p; p += 256 * 256 * 2;
  h16* wtv = (h16*)p; p += 256 * 256 * 2;
  h16* wto = (h16*)p; p += 256 * 256 * 2;
  h16* qb    = (h16*)p; p += (size_t)NN * DD * 2;
  h16* kbh   = (h16*)p; p += (size_t)NN * DD * 2;
  h16* vA    = (h16*)p; p += (size_t)NN * DD * 2;
  h16* featb = (h16*)p; p += (size_t)NN * DD * 2;
  h16* dynT3 = (h16*)p; p += (size_t)NN * NN * 2;
  h16* qaug  = (h16*)p; p += (size_t)NN * 16 * 2;
  h16* kaug  = (h16*)p; p += (size_t)NN * 16 * 2;
  h16* xzT3  = (h16*)p; p += (size_t)NKT2 * 1024 * 2;
  float* den_s = (float*)p; p += (size_t)SPLIT * NH * NN * 4;
  float* axh_s = (float*)p; p += (size_t)SPLIT * NH * NN * 3 * 4;
  float* axl_s = (float*)p; p += (size_t)SPLIT * NH * NN * 3 * 4;
  float* den_tot = (float*)p; p += (size_t)NH * NN * 4;
  float* numT = (float*)p; p += (size_t)DD * NN * 4;

  k_pre<<<PREP_BLKS + CONV_BLKS + WT_BLKS, 256, 0, stream>>>(
      x, xyz, dy, dm, bim, Wq, Wk, Wv, Wo,
      xb, qaug, kaug, xzT3, numT, wtq, wtk, wtv, wto, dynT3);
  k_gemm3<<<dim3(96, 4, 3), 256, 0, stream>>>(xb, wtq, wtk, wtv, bq, bk, bv,
                                              qb, kbh, vA,
                                              0.17677669529663689f * LN2INV);

  float* xyz_final = (float*)d_out;            // output 0: [3072,3]
  float* out_final = (float*)d_out + NN * 3;   // output 1: [3072,256]

  k_msattn<0><<<dim3(NN / 16, SPLIT), 512, 0, stream>>>(
      qb, kbh, vA, dynT3, qaug, kaug, xzT3, den_s, axh_s, axl_s, nullptr);
  k_combine<<<96, 256, 0, stream>>>(den_s, axh_s, axl_s, den_tot,
                                    qaug, kaug, xzT3, nullptr);
  k_msattn<0><<<dim3(NN / 16, SPLIT), 512, 0, stream>>>(
      qb, kbh, vA, dynT3, qaug, kaug, xzT3, den_s, axh_s, axl_s, nullptr);
  k_combine<<<96, 256, 0, stream>>>(den_s, axh_s, axl_s, den_tot,
                                    qaug, kaug, xzT3, nullptr);
  k_msattn<1><<<dim3(NN / 16, SPLIT), 512, 0, stream>>>(
      qb, kbh, vA, dynT3, qaug, kaug, xzT3, den_s, axh_s, axl_s, numT);
  k_combine<<<96, 256, 0, stream>>>(den_s, axh_s, axl_s, den_tot,
                                    nullptr, nullptr, nullptr, xyz_final);
  k_finish<<<dim3(96, 8), 256, 0, stream>>>(numT, den_tot, featb);
  k_gemm<<<dim3(96, 4), 256, 0, stream>>>(featb, wto, bo, out_final, x, NN, 2, 1.f);
}

// Round 11
// 308.276 us; speedup vs baseline: 1.2830x; 1.0132x over previous
//
#include <hip/hip_runtime.h>
#include <hip/hip_fp16.h>

#define NN 3072
#define DD 256
#define NH 8
#define SPLIT 4
#define KT (NN / SPLIT / 64)   // 12 key-tiles of 64 per split
#define NKT2 (NN / 64)         // 48 global key tiles
#define VHALF ((NN / 16) * 256)   // 49152: stride between v-dim halves
#define LN2INV 1.4426950408889634f
#define PREP_BLKS 1152                     // 6 x 192 (512-col chunks)
#define CONV_BLKS ((NN * DD + NN) / 256)   // 3084
#define WT_BLKS 256                        // 8 x 8 x 4

typedef _Float16 h16;
typedef __attribute__((ext_vector_type(4))) _Float16 half4;
typedef __attribute__((ext_vector_type(8))) _Float16 half8;
typedef __attribute__((ext_vector_type(4))) float f32x4;

#if __has_builtin(__builtin_amdgcn_exp2f)
#define EXP2(x) __builtin_amdgcn_exp2f(x)
#else
#define EXP2(x) __expf((x) * 0.69314718056f)
#endif

// K=16 f16 MFMA (legacy naming: no underscore before f16 -- gfx950 keeps it).
// B-fragment layout (k=quad*4+j, n=lane&15) EXACTLY matches the C-fragment of
// the score MFMA -> P feeds PV/sum MFMAs straight from registers.
#define MFMA16(a, b, c) __builtin_amdgcn_mfma_f32_16x16x16f16(a, b, c, 0, 0, 0)

// --------------------------------------------------------- async 16B stage ---
__device__ __forceinline__ void async16(const h16* g, h16* l, int lane) {
#if __has_builtin(__builtin_amdgcn_global_load_lds)
  __builtin_amdgcn_global_load_lds(
      (const __attribute__((address_space(1))) void*)(g + (size_t)lane * 8),
      (__attribute__((address_space(3))) void*)l, 16, 0, 0);
#else
  *(half8*)(l + lane * 8) = *(const half8*)(g + (size_t)lane * 8);
#endif
}

// ------------------------------------------------------------- aug writer ----
// qaug/kaug: 16-dim fp16 aug vectors (geo term via one MFMA, dims 12-15 zero).
// xzT3 layout: A-operand tiles for 16x16x16 MFMA.
// xzT3[kt2][f(4)][quad(4)][m(16)][j(4)]: comp[m] of key kt2*64+f*16+quad*4+j,
// comp = {1, xh, yh, zh, xl, yl, zl, 0...}.
__device__ inline void write_aug(int q, float x, float y, float z,
                                 h16* __restrict__ qaug, h16* __restrict__ kaug,
                                 h16* __restrict__ xzT3) {
  float sx = 0.5f * LN2INV * x, sy = 0.5f * LN2INV * y, sz = 0.5f * LN2INV * z;
  h16 shx = (h16)sx, shy = (h16)sy, shz = (h16)sz;
  h16 slx = (h16)(sx - (float)shx), sly = (h16)(sy - (float)shy), slz = (h16)(sz - (float)shz);
  h16 hx = (h16)x, hy = (h16)y, hz = (h16)z;
  h16 lx = (h16)(x - (float)hx), ly = (h16)(y - (float)hy), lz = (h16)(z - (float)hz);
  float n2n = -0.25f * LN2INV * (x * x + y * y + z * z);
  h16 nh = (h16)n2n, nl = (h16)(n2n - (float)nh);
  h16 qa[16], ka[16];
  #pragma unroll
  for (int i = 0; i < 16; ++i) { qa[i] = (h16)0.f; ka[i] = (h16)0.f; }
  qa[0] = shx; qa[1] = shy; qa[2] = shz;       // pairs A d0-2 = hk
  qa[3] = shx; qa[4] = shy; qa[5] = shz;       // pairs A d3-5 = lk
  qa[6] = slx; qa[7] = sly; qa[8] = slz;       // pairs A d6-8 = hk
  qa[9] = (h16)1.f; qa[10] = (h16)1.f;         // pairs key-norm hi/lo
  qa[11] = (h16)n2n;                           // query norm (row-const)
  ka[0] = hx; ka[1] = hy; ka[2] = hz;
  ka[3] = lx; ka[4] = ly; ka[5] = lz;
  ka[6] = hx; ka[7] = hy; ka[8] = hz;
  ka[9] = nh; ka[10] = nl;
  ka[11] = (h16)1.f;
  *(half8*)(qaug + (size_t)q * 16) = ((half8*)qa)[0];
  *(half8*)(qaug + (size_t)q * 16 + 8) = ((half8*)qa)[1];
  *(half8*)(kaug + (size_t)q * 16) = ((half8*)ka)[0];
  *(half8*)(kaug + (size_t)q * 16 + 8) = ((half8*)ka)[1];
  int kt2 = q >> 6, kk = q & 63;
  int f = kk >> 4, qd = (kk >> 2) & 3, j = kk & 3;
  h16* b = xzT3 + ((size_t)kt2 << 10) + f * 256 + qd * 64 + j;
  b[0] = (h16)1.f;
  b[4] = hx; b[8] = hy; b[12] = hz;
  b[16] = lx; b[20] = ly; b[24] = lz;
  #pragma unroll
  for (int m = 7; m < 16; ++m) b[m * 4] = (h16)0.f;
}

// --------------------------------------------------- fused prologue ----------
// One dispatch: [0,1152) prep-dy (16 rows x 512 cols each -- 2x the blocks of
// r10 for 2x outstanding HBM streams on the 113 MB mask/dy read),
// [1152,1152+3084) convert+aug+numT-zero, tail W-transpose.
__global__ __launch_bounds__(256) void k_pre(
    const float* __restrict__ x, const float* __restrict__ xyz,
    const float* __restrict__ dy, const int* __restrict__ dm,
    const int* __restrict__ bim,
    const float* __restrict__ Wq, const float* __restrict__ Wk,
    const float* __restrict__ Wv, const float* __restrict__ Wo,
    h16* __restrict__ xb, h16* __restrict__ qaug, h16* __restrict__ kaug,
    h16* __restrict__ xzT3, float* __restrict__ numT,
    h16* __restrict__ wtq, h16* __restrict__ wtk, h16* __restrict__ wtv,
    h16* __restrict__ wto, h16* __restrict__ dynT3) {
  __shared__ h16 sv[16][524];           // 16.8 KB; wt branch reuses as fp32
  int b = blockIdx.x;
  int t = threadIdx.x;
  if (b < PREP_BLKS) {
    // ---- prep: 2 rows x 512 cols per pass (vec4), 8 passes ----
    int cb = b % 6, qt = b / 6;
    int half = t >> 7;                 // row within pair
    int cc0 = (t & 127) * 4;           // col within 512-chunk
    int c0 = cb * 512 + cc0;           // global col
    #pragma unroll
    for (int pp = 0; pp < 8; ++pp) {
      int r = pp * 2 + half;
      int row = qt * 16 + r;
      size_t idx = (size_t)row * NN + c0;
      int4 m4 = *(const int4*)(dm + idx);
      int4 b4 = *(const int4*)(bim + idx);
      float4 d4 = *(const float4*)(dy + idx);
      h16* s = &sv[r][cc0];
      int mm[4] = {m4.x & b4.x, m4.y & b4.y, m4.z & b4.z, m4.w & b4.w};
      float dd[4] = {d4.x, d4.y, d4.z, d4.w};
      #pragma unroll
      for (int j = 0; j < 4; ++j) {
        bool diag = (row == c0 + j);
        bool valid = (mm[j] != 0) | diag;
        s[j] = (h16)(valid ? (-LN2INV * (dd[j] + (diag ? 2.5e-5f : 0.f))) : -43281.f);
      }
    }
    __syncthreads();
    #pragma unroll
    for (int s2 = 0; s2 < 4; ++s2) {
      int s = t + s2 * 256;              // 0..1023 : 8 tiles x 128 half8 slots
      int tile = s >> 7;
      int sl = s & 127;                  // chunk*64 + lane
      int lane = sl & 63;
      int row = lane & 15, quad = lane >> 4;
      int base = tile * 64 + (sl >> 6) * 32 + quad * 4;
      half4 lo = *(const half4*)&sv[row][base];
      half4 hi = *(const half4*)&sv[row][base + 16];
      half8 o;
      #pragma unroll
      for (int j = 0; j < 4; ++j) { o[j] = lo[j]; o[j + 4] = hi[j]; }
      h16* dst = dynT3 + (((size_t)qt * NKT2 + (cb * 8 + tile)) << 10) + sl * 8;
      *(half8*)dst = o;
    }
  } else if (b < PREP_BLKS + CONV_BLKS) {
    // ---- convert + initial aug + numT zero ----
    int u = (b - PREP_BLKS) * 256 + t;
    const int NX = NN * DD;
    if (u < NX) { xb[u] = (h16)x[u]; numT[u] = 0.f; return; }
    int q = u - NX;
    if (q < NN)
      write_aug(q, xyz[q * 3], xyz[q * 3 + 1], xyz[q * 3 + 2], qaug, kaug, xzT3);
  } else {
    // ---- W transpose via 32x32 LDS tile (reuses sv storage as fp32) ----
    float* tf = (float*)sv;              // [32][33]
    int w = b - PREP_BLKS - CONV_BLKS;
    int m = w >> 6;
    int n0 = (w & 7) * 32, k0 = ((w >> 3) & 7) * 32;
    const float* W = (m == 0) ? Wq : (m == 1) ? Wk : (m == 2) ? Wv : Wo;
    h16* wt = (m == 0) ? wtq : (m == 1) ? wtk : (m == 2) ? wtv : wto;
    int tx = t & 31, ty = t >> 5;        // 32 x 8
    #pragma unroll
    for (int i = 0; i < 4; ++i)
      tf[(ty + i * 8) * 33 + tx] = W[(size_t)(k0 + ty + i * 8) * 256 + n0 + tx];
    __syncthreads();
    #pragma unroll
    for (int i = 0; i < 4; ++i)
      wt[(size_t)(n0 + ty + i * 8) * 256 + k0 + tx] = (h16)tf[tx * 33 + ty + i * 8];
  }
}

// ------------------------------------------------------------------- gemm ----
// mode 0: fp16 row-major *scale; mode 2: fp32 +resid;
// mode 3: fp16 per-head contiguous kbh[h][token][32];
// mode 4: fp16 MFMA-A-layout vA[h*2+half][tile(192)][quad(4)][dim(16)][j(4)]
__device__ inline void gemm_body(const h16* __restrict__ A, const h16* __restrict__ Bt,
                                 const float* __restrict__ bias, void* __restrict__ out,
                                 const float* __restrict__ resid, int M, int mode,
                                 float scale, int bx, int by) {
  int lane = threadIdx.x & 63;
  int wave = threadIdx.x >> 6;
  int col = lane & 15, quad = lane >> 4;
  int m0 = bx * 32;
  int n0 = by * 64 + wave * 16;
  f32x4 acc[2];
  acc[0] = (f32x4){0.f, 0.f, 0.f, 0.f};
  acc[1] = (f32x4){0.f, 0.f, 0.f, 0.f};
  #pragma unroll
  for (int kk = 0; kk < DD; kk += 32) {
    half8 b = *(const half8*)(Bt + (size_t)(n0 + col) * DD + kk + quad * 8);
    #pragma unroll
    for (int mr = 0; mr < 2; ++mr) {
      half8 a = *(const half8*)(A + (size_t)(m0 + mr * 16 + col) * DD + kk + quad * 8);
      acc[mr] = __builtin_amdgcn_mfma_f32_16x16x32_f16(a, b, acc[mr], 0, 0, 0);
    }
  }
  float bb = bias[n0 + col];
  #pragma unroll
  for (int mr = 0; mr < 2; ++mr) {
    #pragma unroll
    for (int r = 0; r < 4; ++r) {
      int m = m0 + mr * 16 + quad * 4 + r;
      int n = n0 + col;
      float v = acc[mr][r] + bb;
      if (mode == 0)      ((h16*)out)[(size_t)m * DD + n] = (h16)(v * scale);
      else if (mode == 3) ((h16*)out)[((size_t)(n >> 5) * NN + m) * 32 + (n & 31)] = (h16)v;
      else if (mode == 4) {
        int hh = n >> 5, d = n & 31;
        size_t a = ((((size_t)hh * 2 + (d >> 4)) * (NN / 16) + (m >> 4)) * 64 +
                    ((m >> 2) & 3) * 16 + (d & 15)) * 4 + (m & 3);
        ((h16*)out)[a] = (h16)v;
      }
      else ((float*)out)[(size_t)m * DD + n] = v + resid[(size_t)m * DD + n];
    }
  }
}

__global__ __launch_bounds__(256) void k_gemm(
    const h16* __restrict__ A, const h16* __restrict__ Bt,
    const float* __restrict__ bias, void* __restrict__ out,
    const float* __restrict__ resid, int M, int mode, float scale) {
  gemm_body(A, Bt, bias, out, resid, M, mode, scale, blockIdx.x, blockIdx.y);
}

__global__ __launch_bounds__(256) void k_gemm3(
    const h16* __restrict__ A, const h16* __restrict__ wtq,
    const h16* __restrict__ wtk, const h16* __restrict__ wtv,
    const float* __restrict__ bq, const float* __restrict__ bk,
    const float* __restrict__ bv, h16* __restrict__ qb, h16* __restrict__ kbh,
    h16* __restrict__ vA, float qscale) {
  int z = blockIdx.z;
  const h16* Bt = (z == 0) ? wtq : (z == 1) ? wtk : wtv;
  const float* bias = (z == 0) ? bq : (z == 1) ? bk : bv;
  void* out = (z == 0) ? (void*)qb : (z == 1) ? (void*)kbh : (void*)vA;
  int mode = (z == 0) ? 0 : (z == 1) ? 3 : 4;
  gemm_body(A, Bt, bias, out, nullptr, NN, mode, (z == 0) ? qscale : 1.f,
            blockIdx.x, blockIdx.y);
}

// ------------------------------------------------------------- mean shift ----
// r9 core (transpose-free PV, no setprio, no de-phasing -- r10 proved the
// s_sleep stagger null).
__device__ __forceinline__ void stage_tile(int h, int lane, int qt, int kt2,
                                           const h16* __restrict__ dynT3,
                                           const h16* __restrict__ kaug,
                                           const h16* __restrict__ xzT3,
                                           h16* bdy, h16* bka, h16* bxz) {
  if (h < 2)
    async16(dynT3 + (((size_t)qt * NKT2 + kt2) << 10) + h * 512, bdy + h * 512, lane);
  else if (h < 4)
    async16(kaug + ((size_t)kt2 << 10) + (h - 2) * 512, bka + (h - 2) * 512, lane);
  else if (h < 6)
    async16(xzT3 + ((size_t)kt2 << 10) + (h - 4) * 512, bxz + (h - 4) * 512, lane);
}

__device__ __forceinline__ void ldkf(const h16* __restrict__ kbh_h, int k0,
                                     int col, int quad, half8 kf[4]) {
  #pragma unroll
  for (int f = 0; f < 4; ++f)
    kf[f] = *(const half8*)(kbh_h + (size_t)(k0 + f * 16 + col) * 32 + quad * 8);
}

template <int LAST>
__device__ __forceinline__ void ms_compute(
    const h16* __restrict__ bdy, const h16* __restrict__ bka,
    const h16* __restrict__ bxz, const half8 kf[4], half8 qaf, half8 qf,
    const h16* __restrict__ vA0, int lane, int col, int quad,
    f32x4& accS, f32x4& fc0, f32x4& fc1) {
  half8 kz = {};
  half8 dv0 = *(const half8*)(bdy + lane * 8);
  half8 dv1 = *(const half8*)(bdy + 512 + lane * 8);
  #pragma unroll
  for (int f = 0; f < 4; ++f) {
    half8 ka = (quad < 2) ? *(const half8*)(bka + (f * 16 + col) * 16 + quad * 8) : kz;
    half8 dv = (f & 2) ? dv1 : dv0;
    f32x4 cc;
    #pragma unroll
    for (int r = 0; r < 4; ++r) cc[r] = (float)dv[(f & 1) * 4 + r];
    f32x4 g = __builtin_amdgcn_mfma_f32_16x16x32_f16(ka, qaf, cc, 0, 0, 0);
    f32x4 s = __builtin_amdgcn_mfma_f32_16x16x32_f16(kf[f], qf, g, 0, 0, 0);
    half4 pv;
    #pragma unroll
    for (int r = 0; r < 4; ++r) pv[r] = (h16)EXP2(s[r]);
    half4 xa = *(const half4*)(bxz + f * 256 + lane * 4);
    accS = MFMA16(xa, pv, accS);
    if (LAST) {
      half4 v0 = *(const half4*)(vA0 + f * 256 + lane * 4);
      half4 v1 = *(const half4*)(vA0 + VHALF + f * 256 + lane * 4);
      fc0 = MFMA16(v0, pv, fc0);
      fc1 = MFMA16(v1, pv, fc1);
    }
  }
}

template <int LAST>
__global__ __launch_bounds__(512, 4) void k_msattn(
    const h16* __restrict__ qb, const h16* __restrict__ kbh,
    const h16* __restrict__ vA, const h16* __restrict__ dynT3,
    const h16* __restrict__ qaug, const h16* __restrict__ kaug,
    const h16* __restrict__ xzT3, float* __restrict__ den_s,
    float* __restrict__ axh_s, float* __restrict__ axl_s,
    float* __restrict__ numT) {
  __shared__ h16 s_dy[2][1024];
  __shared__ h16 s_ka[2][1024];
  __shared__ h16 s_xz[2][1024];
  const int tid = threadIdx.x;
  const int h = tid >> 6;
  const int lane = tid & 63;
  const int col = lane & 15;
  const int quad = lane >> 4;
  const int qt = blockIdx.x;
  const int q0 = qt * 16;
  const int tb = blockIdx.y * KT;

  half8 kz = {};
  half8 qf = *(const half8*)(qb + (size_t)(q0 + col) * DD + h * 32 + quad * 8);
  half8 qaf = (quad < 2) ? *(const half8*)(qaug + (size_t)(q0 + col) * 16 + quad * 8) : kz;
  const h16* kbh_h = kbh + (size_t)h * NN * 32;
  const h16* vb = vA + (size_t)h * 2 * (NN / 16) * 256;   // head base
  f32x4 accS = (f32x4){0.f, 0.f, 0.f, 0.f};
  f32x4 fc0 = (f32x4){0.f, 0.f, 0.f, 0.f};
  f32x4 fc1 = (f32x4){0.f, 0.f, 0.f, 0.f};
  half8 kfA[4], kfB[4];

  stage_tile(h, lane, qt, tb, dynT3, kaug, xzT3, s_dy[0], s_ka[0], s_xz[0]);
  ldkf(kbh_h, tb * 64, col, quad, kfA);
  __syncthreads();          // drains async stage + kfA
  #pragma unroll 1
  for (int kt = 0; kt < KT; kt += 2) {
    int t1 = tb + kt + 1;
    stage_tile(h, lane, qt, t1, dynT3, kaug, xzT3, s_dy[1], s_ka[1], s_xz[1]);
    ldkf(kbh_h, t1 * 64, col, quad, kfB);
    ms_compute<LAST>(s_dy[0], s_ka[0], s_xz[0], kfA, qaf, qf,
                     vb + (size_t)(tb + kt) * 1024,
                     lane, col, quad, accS, fc0, fc1);
    __syncthreads();        // buf1 + kfB now resident
    int t2 = (kt + 2 < KT) ? tb + kt + 2 : t1;
    if (kt + 2 < KT)
      stage_tile(h, lane, qt, t2, dynT3, kaug, xzT3, s_dy[0], s_ka[0], s_xz[0]);
    ldkf(kbh_h, t2 * 64, col, quad, kfA);
    ms_compute<LAST>(s_dy[1], s_ka[1], s_xz[1], kfB, qaf, qf,
                     vb + (size_t)t1 * 1024,
                     lane, col, quad, accS, fc0, fc1);
    __syncthreads();
  }

  // accS D rows: 0=den, 1-3=num_hi, 4-6=num_lo
  int q = q0 + col;
  size_t sidx = (size_t)(blockIdx.y * NH + h) * NN + q;
  if (quad == 0) {
    den_s[sidx] = accS[0];
    axh_s[sidx * 3 + 0] = accS[1];
    axh_s[sidx * 3 + 1] = accS[2];
    axh_s[sidx * 3 + 2] = accS[3];
  } else if (quad == 1) {
    axl_s[sidx * 3 + 0] = accS[0];
    axl_s[sidx * 3 + 1] = accS[1];
    axl_s[sidx * 3 + 2] = accS[2];
  }
  if (LAST) {
    #pragma unroll
    for (int r = 0; r < 4; ++r) {
      atomicAdd(&numT[(size_t)(h * 32 + quad * 4 + r) * NN + q], fc0[r]);
      atomicAdd(&numT[(size_t)(h * 32 + 16 + quad * 4 + r) * NN + q], fc1[r]);
    }
  }
}

// ---------------------------------------------------------------- combine ----
// Parallel version: 96 blocks x (32 q x 8 h) threads; per-thread 4-split sum,
// then width-8 shfl_xor reduction over heads.
__global__ __launch_bounds__(256) void k_combine(
    const float* __restrict__ den_s, const float* __restrict__ axh_s,
    const float* __restrict__ axl_s, float* __restrict__ den_tot,
    h16* __restrict__ qaug, h16* __restrict__ kaug, h16* __restrict__ xzT3,
    float* __restrict__ out3) {
  int h = threadIdx.x & 7;
  int q = blockIdx.x * 32 + (threadIdx.x >> 3);
  float d = 0.f, x = 0.f, y = 0.f, z = 0.f;
  #pragma unroll
  for (int s = 0; s < SPLIT; ++s) {
    size_t idx = (size_t)(s * NH + h) * NN + q;
    d += den_s[idx];
    x += axh_s[idx * 3 + 0] + axl_s[idx * 3 + 0];
    y += axh_s[idx * 3 + 1] + axl_s[idx * 3 + 1];
    z += axh_s[idx * 3 + 2] + axl_s[idx * 3 + 2];
  }
  den_tot[h * NN + q] = d;
  float inv = 0.125f / d;
  float X = x * inv, Y = y * inv, Z = z * inv;
  #pragma unroll
  for (int m = 1; m < 8; m <<= 1) {
    X += __shfl_xor(X, m);
    Y += __shfl_xor(Y, m);
    Z += __shfl_xor(Z, m);
  }
  if (h == 0) {
    if (out3) {
      out3[q * 3 + 0] = X;
      out3[q * 3 + 1] = Y;
      out3[q * 3 + 2] = Z;
    } else {
      write_aug(q, X, Y, Z, qaug, kaug, xzT3);
    }
  }
}

// ----------------------------------------------------------------- finish ----
__global__ __launch_bounds__(256) void k_finish(
    const float* __restrict__ numT, const float* __restrict__ den_tot,
    h16* __restrict__ featb) {
  __shared__ float tile[32][33];
  int q0 = blockIdx.x * 32, d0 = blockIdx.y * 32;
  int tx = threadIdx.x & 31, ty = threadIdx.x >> 5;   // 32 x 8
  #pragma unroll
  for (int i = 0; i < 4; ++i)
    tile[ty + i * 8][tx] = numT[(size_t)(d0 + ty + i * 8) * NN + q0 + tx];
  __syncthreads();
  int h = d0 >> 5;
  #pragma unroll
  for (int i = 0; i < 4; ++i) {
    int q = q0 + ty + i * 8;
    float inv = 1.f / den_tot[h * NN + q];
    featb[(size_t)q * DD + d0 + tx] = (h16)(tile[tx][ty + i * 8] * inv);
  }
}

// ----------------------------------------------------------------- launch ----
extern "C" void kernel_launch(void* const* d_in, const int* in_sizes, int n_in,
                              void* d_out, int out_size, void* d_ws, size_t ws_size,
                              hipStream_t stream) {
  const float* x   = (const float*)d_in[0];
  const float* xyz = (const float*)d_in[1];
  const float* dy  = (const float*)d_in[2];
  const int* dm    = (const int*)d_in[3];
  const int* bim   = (const int*)d_in[4];
  const float* Wq = (const float*)d_in[5];
  const float* bq = (const float*)d_in[6];
  const float* Wk = (const float*)d_in[7];
  const float* bk = (const float*)d_in[8];
  const float* Wv = (const float*)d_in[9];
  const float* bv = (const float*)d_in[10];
  const float* Wo = (const float*)d_in[11];
  const float* bo = (const float*)d_in[12];

  char* p = (char*)d_ws;
  h16* xb  = (h16*)p; p += (size_t)NN * DD * 2;
  h16* wtq = (h16*)p; p += 256 * 256 * 2;
  h16* wtk = (h16*)p; p += 256 * 256 * 2;
  h16* wtv = (h16*)p; p += 256 * 256 * 2;
  h16* wto = (h16*)p; p += 256 * 256 * 2;
  h16* qb    = (h16*)p; p += (size_t)NN * DD * 2;
  h16* kbh   = (h16*)p; p += (size_t)NN * DD * 2;
  h16* vA    = (h16*)p; p += (size_t)NN * DD * 2;
  h16* featb = (h16*)p; p += (size_t)NN * DD * 2;
  h16* dynT3 = (h16*)p; p += (size_t)NN * NN * 2;
  h16* qaug  = (h16*)p; p += (size_t)NN * 16 * 2;
  h16* kaug  = (h16*)p; p += (size_t)NN * 16 * 2;
  h16* xzT3  = (h16*)p; p += (size_t)NKT2 * 1024 * 2;
  float* den_s = (float*)p; p += (size_t)SPLIT * NH * NN * 4;
  float* axh_s = (float*)p; p += (size_t)SPLIT * NH * NN * 3 * 4;
  float* axl_s = (float*)p; p += (size_t)SPLIT * NH * NN * 3 * 4;
  float* den_tot = (float*)p; p += (size_t)NH * NN * 4;
  float* numT = (float*)p; p += (size_t)DD * NN * 4;

  k_pre<<<PREP_BLKS + CONV_BLKS + WT_BLKS, 256, 0, stream>>>(
      x, xyz, dy, dm, bim, Wq, Wk, Wv, Wo,
      xb, qaug, kaug, xzT3, numT, wtq, wtk, wtv, wto, dynT3);
  k_gemm3<<<dim3(96, 4, 3), 256, 0, stream>>>(xb, wtq, wtk, wtv, bq, bk, bv,
                                              qb, kbh, vA,
                                              0.17677669529663689f * LN2INV);

  float* xyz_final = (float*)d_out;            // output 0: [3072,3]
  float* out_final = (float*)d_out + NN * 3;   // output 1: [3072,256]

  k_msattn<0><<<dim3(NN / 16, SPLIT), 512, 0, stream>>>(
      qb, kbh, vA, dynT3, qaug, kaug, xzT3, den_s, axh_s, axl_s, nullptr);
  k_combine<<<96, 256, 0, stream>>>(den_s, axh_s, axl_s, den_tot,
                                    qaug, kaug, xzT3, nullptr);
  k_msattn<0><<<dim3(NN / 16, SPLIT), 512, 0, stream>>>(
      qb, kbh, vA, dynT3, qaug, kaug, xzT3, den_s, axh_s, axl_s, nullptr);
  k_combine<<<96, 256, 0, stream>>>(den_s, axh_s, axl_s, den_tot,
                                    qaug, kaug, xzT3, nullptr);
  k_msattn<1><<<dim3(NN / 16, SPLIT), 512, 0, stream>>>(
      qb, kbh, vA, dynT3, qaug, kaug, xzT3, den_s, axh_s, axl_s, numT);
  k_combine<<<96, 256, 0, stream>>>(den_s, axh_s, axl_s, den_tot,
                                    nullptr, nullptr, nullptr, xyz_final);
  k_finish<<<dim3(96, 8), 256, 0, stream>>>(numT, den_tot, featb);
  k_gemm<<<dim3(96, 4), 256, 0, stream>>>(featb, wto, bo, out_final, x, NN, 2, 1.f);
}